// Round 7
// baseline (638.028 us; speedup 1.0000x reference)
//
#include <hip/hip_runtime.h>
#include <cstdint>

#define D 128
#define H 4
#define N_ENT 100000
#define N_EDGE 400000
#define R 32

#define SCAN_NB ((N_ENT + 511) / 512)  // 196 blocks of 512 elements

// ---------------------------------------------------------------------------
// CSR build: histogram -> hierarchical scan -> scatter (permuted packed
// (tail,etype) int2).
// ---------------------------------------------------------------------------
__global__ void k_hist(const int* __restrict__ head, int* __restrict__ deg) {
  const int e = blockIdx.x * 256 + threadIdx.x;
  if (e < N_EDGE) atomicAdd(&deg[head[e]], 1);
}

__global__ __launch_bounds__(256) void k_scan1(const int* __restrict__ deg,
                                               int* __restrict__ bsum) {
  const int t = threadIdx.x;
  const int i = blockIdx.x * 512 + t * 2;
  int v0 = (i < N_ENT) ? deg[i] : 0;
  int v1 = (i + 1 < N_ENT) ? deg[i + 1] : 0;
  int s = v0 + v1;
#pragma unroll
  for (int k = 1; k < 64; k <<= 1) s += __shfl_xor(s, k);
  __shared__ int ws[4];
  if ((t & 63) == 0) ws[t >> 6] = s;
  __syncthreads();
  if (t == 0) bsum[blockIdx.x] = ws[0] + ws[1] + ws[2] + ws[3];
}

__global__ __launch_bounds__(256) void k_scan2(const int* __restrict__ bsum,
                                               int* __restrict__ bbase,
                                               int* __restrict__ off) {
  __shared__ int sh[256];
  const int t = threadIdx.x;
  const int v = (t < SCAN_NB) ? bsum[t] : 0;
  sh[t] = v;
  __syncthreads();
  for (int d = 1; d < 256; d <<= 1) {
    const int u = (t >= d) ? sh[t - d] : 0;
    __syncthreads();
    sh[t] += u;
    __syncthreads();
  }
  if (t < SCAN_NB) bbase[t] = sh[t] - v;
  if (t == SCAN_NB - 1) off[N_ENT] = sh[t];
}

__global__ __launch_bounds__(256) void k_scan3(const int* __restrict__ deg,
                                               const int* __restrict__ bbase,
                                               int* __restrict__ off,
                                               int* __restrict__ cur) {
  __shared__ int sh[256];
  const int t = threadIdx.x;
  const int i = blockIdx.x * 512 + t * 2;
  const int v0 = (i < N_ENT) ? deg[i] : 0;
  const int v1 = (i + 1 < N_ENT) ? deg[i + 1] : 0;
  const int s = v0 + v1;
  sh[t] = s;
  __syncthreads();
  for (int d = 1; d < 256; d <<= 1) {
    const int u = (t >= d) ? sh[t - d] : 0;
    __syncthreads();
    sh[t] += u;
    __syncthreads();
  }
  const int ex = sh[t] - s + bbase[blockIdx.x];
  if (i < N_ENT) {
    off[i] = ex;
    cur[i] = ex;
  }
  if (i + 1 < N_ENT) {
    off[i + 1] = ex + v0;
    cur[i + 1] = ex + v0;
  }
}

__global__ void k_scatter(const int* __restrict__ head,
                          const int* __restrict__ tail,
                          const int* __restrict__ etype, int* __restrict__ cur,
                          int2* __restrict__ teP) {
  const int e = blockIdx.x * 256 + threadIdx.x;
  if (e >= N_EDGE) return;
  const int hd = head[e];
  const int pos = atomicAdd(&cur[hd], 1);
  teP[pos] = make_int2(tail[e], etype[e] - 1);
}

// ---------------------------------------------------------------------------
// k_prep: blocks 0-15: kTt[j*128+i] = kT[i*128+j]; block 16: wrel2 = wrel^2.
// Runs AFTER k_scatter: wrel2 aliases the dead `cur` array.
// ---------------------------------------------------------------------------
__global__ __launch_bounds__(256) void k_prep(const float* __restrict__ kT,
                                              float* __restrict__ kTt,
                                              const float* __restrict__ wrel,
                                              float* __restrict__ wrel2) {
  if (blockIdx.x < 16) {
    __shared__ float tile[32][33];
    const int bx = blockIdx.x & 3, by = blockIdx.x >> 2;
    const int c = threadIdx.x & 31;
    const int r0 = (threadIdx.x >> 5) * 4;
#pragma unroll
    for (int i = 0; i < 4; ++i)
      tile[r0 + i][c] = kT[(by * 32 + r0 + i) * 128 + bx * 32 + c];
    __syncthreads();
#pragma unroll
    for (int i = 0; i < 4; ++i)
      kTt[(bx * 32 + r0 + i) * 128 + by * 32 + c] = tile[c][r0 + i];
  } else {
    const int t = threadIdx.x;
#pragma unroll
    for (int s = 0; s < 4; ++s) {
      const int idx = (s * 256 + t) * 4;
      float4 v = *(const float4*)&wrel[idx];
      v.x *= v.x; v.y *= v.y; v.z *= v.z; v.w *= v.w;
      *(float4*)&wrel2[idx] = v;
    }
  }
}

// ---------------------------------------------------------------------------
// K1: Q = entity_emb @ qTrans   (Q in d_out; consumed & overwritten later)
// ---------------------------------------------------------------------------
__global__ __launch_bounds__(512) void k_qproj(const float* __restrict__ ent,
                                               const float* __restrict__ qT,
                                               float* __restrict__ Q) {
  __shared__ float sT[D * D];
  __shared__ float rows[D * 128];
  const int t = threadIdx.x;
  const int n0 = blockIdx.x * 128;
#pragma unroll
  for (int s = 0; s < 8; ++s) {
    const int idx = (s * 512 + t) * 4;
    *(float4*)&sT[idx] = *(const float4*)&qT[idx];
  }
  {
    const int g = t & 3;
    const int n = t >> 2;
    const int node = n0 + n;
    if (node < N_ENT) {
      const float* src = ent + (size_t)node * D;
#pragma unroll
      for (int s = 0; s < 8; ++s) {
        const int i = s * 16 + g * 4;
        float4 v = *(const float4*)&src[i];
        rows[(i + 0) * 128 + n] = v.x;
        rows[(i + 1) * 128 + n] = v.y;
        rows[(i + 2) * 128 + n] = v.z;
        rows[(i + 3) * 128 + n] = v.w;
      }
    } else {
#pragma unroll
      for (int s = 0; s < 8; ++s) {
        const int i = s * 16 + g * 4;
        rows[(i + 0) * 128 + n] = 0.f;
        rows[(i + 1) * 128 + n] = 0.f;
        rows[(i + 2) * 128 + n] = 0.f;
        rows[(i + 3) * 128 + n] = 0.f;
      }
    }
  }
  __syncthreads();
  const int jj = t & 15;
  const int ee = t >> 4;
  float acc[4][8];
#pragma unroll
  for (int a = 0; a < 4; ++a)
#pragma unroll
    for (int b = 0; b < 8; ++b) acc[a][b] = 0.f;
#pragma unroll 4
  for (int i = 0; i < D; ++i) {
    float4 b0 = *(float4*)&sT[i * D + jj * 8];
    float4 b1 = *(float4*)&sT[i * D + jj * 8 + 4];
    float4 a0 = *(float4*)&rows[i * 128 + ee * 4];
    float bv[8] = {b0.x, b0.y, b0.z, b0.w, b1.x, b1.y, b1.z, b1.w};
    float av[4] = {a0.x, a0.y, a0.z, a0.w};
#pragma unroll
    for (int a = 0; a < 4; ++a)
#pragma unroll
      for (int b = 0; b < 8; ++b) acc[a][b] = fmaf(av[a], bv[b], acc[a][b]);
  }
#pragma unroll
  for (int a = 0; a < 4; ++a) {
    const int node = n0 + ee * 4 + a;
    if (node < N_ENT) {
      float4 o0 = {acc[a][0], acc[a][1], acc[a][2], acc[a][3]};
      float4 o1 = {acc[a][4], acc[a][5], acc[a][6], acc[a][7]};
      *(float4*)&Q[(size_t)node * D + jj * 8] = o0;
      *(float4*)&Q[(size_t)node * D + jj * 8 + 4] = o1;
    }
  }
}

// ---------------------------------------------------------------------------
// K2: fused attention + S. 256 threads, 8 nodes/block (one node per 32-lane
// HALF-WAVE, float4 per lane), 20 KB LDS.
// R6 lesson: edge loop is latency-chain bound; 2 nodes/wave (half-wave f4)
// does ~260K wave-iterations vs 400K for 1 node/wave -> structure wins over
// occupancy. R2 lesson: clamp-32 + half-wave f4 was fastest (234us) DESPITE
// 184MB spill; here the 16 P-registers (the spill driver) are replaced by
// in-loop ds_read_b128 from sPA (P stays valid in LDS all loop long), so
// clamp-32 should be ~spill-free -> ~80% occupancy without R2's overhead.
// ---------------------------------------------------------------------------
__global__ __launch_bounds__(256, 8) void k_fused(
    const float* __restrict__ ent, const float* __restrict__ wrel,
    const float* __restrict__ kTt, const float* __restrict__ vT,
    const float* __restrict__ wrel2, const float* __restrict__ qkg,
    float* __restrict__ S, const int* __restrict__ off,
    const int2* __restrict__ teP) {
  __shared__ float sQ[8 * 128];    //  4 KB: Q, later kg^2
  __shared__ float sPA[8 * 512];   // 16 KB: P (read all of P2), then Agg
  const int t = threadIdx.x;
  const int base = blockIdx.x * 8;
  const int wid = t >> 6;
  const int half = (t >> 5) & 1;
  const int l32 = t & 31;
  const int kk = wid * 2 + half;
  const int n = base + kk;

  // P0: stage Q rows (8 x 128 floats, one float4 per thread)
  {
    const int k = t >> 5;
    const int c4 = (t & 31) * 4;
    *(float4*)&sQ[k * 128 + c4] =
        *(const float4*)&qkg[(size_t)(base + k) * D + c4];
  }

  // hoisted: CSR range + first edge gather (latency overlaps P1)
  const int eb = off[n];
  const int deg = off[n + 1] - eb;
  float4 xv = {0, 0, 0, 0}, rv = {0, 0, 0, 0};
  if (deg > 0) {
    const int2 pf = teP[eb];
    xv = *(const float4*)&ent[(size_t)pf.x * D + l32 * 4];
    rv = *(const float4*)&wrel[(size_t)pf.y * D + l32 * 4];
  }
  __syncthreads();

  // P1: P[k,h,i] = sum_c kTt[h*32+c, i] * Q[k, h*32+c] -> sPA.
  {
    const int i = t & 127;
    const int sub = t >> 7;
    float pp[2][8];
#pragma unroll
    for (int hh = 0; hh < 2; ++hh)
#pragma unroll
      for (int k = 0; k < 8; ++k) pp[hh][k] = 0.f;
#pragma unroll
    for (int hh = 0; hh < 2; ++hh) {
      const int h = sub * 2 + hh;
#pragma unroll 2
      for (int c4 = 0; c4 < 8; ++c4) {
        const float kv0 = kTt[(h * 32 + c4 * 4 + 0) * 128 + i];
        const float kv1 = kTt[(h * 32 + c4 * 4 + 1) * 128 + i];
        const float kv2 = kTt[(h * 32 + c4 * 4 + 2) * 128 + i];
        const float kv3 = kTt[(h * 32 + c4 * 4 + 3) * 128 + i];
#pragma unroll
        for (int k = 0; k < 8; ++k) {
          const float4 q = *(const float4*)&sQ[k * 128 + h * 32 + c4 * 4];
          pp[hh][k] = fmaf(kv0, q.x, pp[hh][k]);
          pp[hh][k] = fmaf(kv1, q.y, pp[hh][k]);
          pp[hh][k] = fmaf(kv2, q.z, pp[hh][k]);
          pp[hh][k] = fmaf(kv3, q.w, pp[hh][k]);
        }
      }
    }
#pragma unroll
    for (int hh = 0; hh < 2; ++hh)
#pragma unroll
      for (int k = 0; k < 8; ++k)
        sPA[k * 512 + (sub * 2 + hh) * 128 + i] = pp[hh][k];
  }
  __syncthreads();

  // P2: edge loop. half-wave owns one node; P read from LDS per edge
  // (loop-invariant addresses; under clamp-32 the allocator keeps these as
  // in-loop ds_reads instead of 16 scratch-spilled registers).
  // lane lp = l32&3 carries head (lp^m) in accumulator b_m.
  {
    const int lp = l32 & 3;
    const float* Pb = &sPA[kk * 512 + l32 * 4];
    float4 b0 = {0, 0, 0, 0}, b1 = {0, 0, 0, 0};
    float4 b2 = {0, 0, 0, 0}, b3 = {0, 0, 0, 0};
    float s0 = 0.f, s1 = 0.f, s2 = 0.f, s3 = 0.f;
    for (int idx = 0; idx < deg; ++idx) {
      const float4 nh = {xv.x * rv.x, xv.y * rv.y, xv.z * rv.z, xv.w * rv.w};
      if (idx + 1 < deg) {
        const int2 pf = teP[eb + idx + 1];
        xv = *(const float4*)&ent[(size_t)pf.x * D + l32 * 4];
        rv = *(const float4*)&wrel[(size_t)pf.y * D + l32 * 4];
      }
      const float4 p0 = *(const float4*)&Pb[0];
      const float4 p1 = *(const float4*)&Pb[128];
      const float4 p2 = *(const float4*)&Pb[256];
      const float4 p3 = *(const float4*)&Pb[384];
      float d0 = nh.x * p0.x + nh.y * p0.y + nh.z * p0.z + nh.w * p0.w;
      float d1 = nh.x * p1.x + nh.y * p1.y + nh.z * p1.z + nh.w * p1.w;
      float d2 = nh.x * p2.x + nh.y * p2.y + nh.z * p2.z + nh.w * p2.w;
      float d3 = nh.x * p3.x + nh.y * p3.y + nh.z * p3.z + nh.w * p3.w;
      // packed 4-value butterfly: lane ends with full sum of d_{l32&3}
      float x01 = (l32 & 1) ? d1 : d0;
      float y01 = (l32 & 1) ? d0 : d1;
      x01 += __shfl_xor(y01, 1);
      float x23 = (l32 & 1) ? d3 : d2;
      float y23 = (l32 & 1) ? d2 : d3;
      x23 += __shfl_xor(y23, 1);
      float xa = (l32 & 2) ? x23 : x01;
      float xb = (l32 & 2) ? x01 : x23;
      xa += __shfl_xor(xb, 2);
      xa += __shfl_xor(xa, 4);
      xa += __shfl_xor(xa, 8);
      xa += __shfl_xor(xa, 16);
      const float eL = __expf(fminf(fmaxf(xa, -10.f), 10.f));
      const float e0 = eL;                 // head lp
      const float e1 = __shfl_xor(eL, 1);  // head lp^1
      const float e2 = __shfl_xor(eL, 2);  // head lp^2
      const float e3 = __shfl_xor(eL, 3);  // head lp^3
      b0.x = fmaf(e0, nh.x, b0.x); b0.y = fmaf(e0, nh.y, b0.y);
      b0.z = fmaf(e0, nh.z, b0.z); b0.w = fmaf(e0, nh.w, b0.w);
      b1.x = fmaf(e1, nh.x, b1.x); b1.y = fmaf(e1, nh.y, b1.y);
      b1.z = fmaf(e1, nh.z, b1.z); b1.w = fmaf(e1, nh.w, b1.w);
      b2.x = fmaf(e2, nh.x, b2.x); b2.y = fmaf(e2, nh.y, b2.y);
      b2.z = fmaf(e2, nh.z, b2.z); b2.w = fmaf(e2, nh.w, b2.w);
      b3.x = fmaf(e3, nh.x, b3.x); b3.y = fmaf(e3, nh.y, b3.y);
      b3.z = fmaf(e3, nh.z, b3.z); b3.w = fmaf(e3, nh.w, b3.w);
      s0 += e0; s1 += e1; s2 += e2; s3 += e3;
    }
    // all lanes of the half-wave exit together (deg uniform per node);
    // stores stay within this node's kk region -> no barrier needed here.
    const float i0 = 1.f / (s0 + 1e-8f);
    const float i1 = 1.f / (s1 + 1e-8f);
    const float i2 = 1.f / (s2 + 1e-8f);
    const float i3 = 1.f / (s3 + 1e-8f);
    float4 o0 = {b0.x * i0, b0.y * i0, b0.z * i0, b0.w * i0};
    float4 o1 = {b1.x * i1, b1.y * i1, b1.z * i1, b1.w * i1};
    float4 o2 = {b2.x * i2, b2.y * i2, b2.z * i2, b2.w * i2};
    float4 o3 = {b3.x * i3, b3.y * i3, b3.z * i3, b3.w * i3};
    const int sb = kk * 512 + l32 * 4;
    *(float4*)&sPA[sb + ((lp ^ 0) << 7)] = o0;
    *(float4*)&sPA[sb + ((lp ^ 1) << 7)] = o1;
    *(float4*)&sPA[sb + ((lp ^ 2) << 7)] = o2;
    *(float4*)&sPA[sb + ((lp ^ 3) << 7)] = o3;
  }
  __syncthreads();

  // P3: kg[n,c] = sum_d agg[n,h(c),d]*vT[d,c] (regs); kg^2 -> sQ (Q dead).
  {
    const int c = t & 127;
    const int g4 = (t >> 7) * 4;
    const int h = c >> 5;
    float acc0 = 0.f, acc1 = 0.f, acc2 = 0.f, acc3 = 0.f;
    const float* agg0 = &sPA[(g4 + 0) * 512 + h * 128];
    const float* agg1 = &sPA[(g4 + 1) * 512 + h * 128];
    const float* agg2 = &sPA[(g4 + 2) * 512 + h * 128];
    const float* agg3 = &sPA[(g4 + 3) * 512 + h * 128];
#pragma unroll 4
    for (int d4 = 0; d4 < 32; ++d4) {
      const float4 a0 = *(const float4*)&agg0[d4 * 4];
      const float4 a1 = *(const float4*)&agg1[d4 * 4];
      const float4 a2 = *(const float4*)&agg2[d4 * 4];
      const float4 a3 = *(const float4*)&agg3[d4 * 4];
      const float v0 = vT[(d4 * 4 + 0) * 128 + c];
      const float v1 = vT[(d4 * 4 + 1) * 128 + c];
      const float v2 = vT[(d4 * 4 + 2) * 128 + c];
      const float v3 = vT[(d4 * 4 + 3) * 128 + c];
      acc0 = fmaf(a0.x, v0, acc0); acc0 = fmaf(a0.y, v1, acc0);
      acc0 = fmaf(a0.z, v2, acc0); acc0 = fmaf(a0.w, v3, acc0);
      acc1 = fmaf(a1.x, v0, acc1); acc1 = fmaf(a1.y, v1, acc1);
      acc1 = fmaf(a1.z, v2, acc1); acc1 = fmaf(a1.w, v3, acc1);
      acc2 = fmaf(a2.x, v0, acc2); acc2 = fmaf(a2.y, v1, acc2);
      acc2 = fmaf(a2.z, v2, acc2); acc2 = fmaf(a2.w, v3, acc2);
      acc3 = fmaf(a3.x, v0, acc3); acc3 = fmaf(a3.y, v1, acc3);
      acc3 = fmaf(a3.z, v2, acc3); acc3 = fmaf(a3.w, v3, acc3);
    }
    sQ[(g4 + 0) * 128 + c] = acc0 * acc0;
    sQ[(g4 + 1) * 128 + c] = acc1 * acc1;
    sQ[(g4 + 2) * 128 + c] = acc2 * acc2;
    sQ[(g4 + 3) * 128 + c] = acc3 * acc3;
  }
  __syncthreads();

  // P4: S[n,r] = sum_c kg2[n,c] * wrel2[r,c]; coalesced store.
  {
    const int nn = t >> 5;  // 0..7
    const int r = t & 31;
    const float* kg2 = &sQ[nn * 128];
    const float* w2 = &wrel2[r * 128];
    float acc = 0.f;
#pragma unroll 4
    for (int c4 = 0; c4 < 32; ++c4) {
      const float4 a = *(const float4*)&kg2[c4 * 4];
      const float4 b = *(const float4*)&w2[c4 * 4];
      acc = fmaf(a.x, b.x, acc); acc = fmaf(a.y, b.y, acc);
      acc = fmaf(a.z, b.z, acc); acc = fmaf(a.w, b.w, acc);
    }
    S[(size_t)(base + nn) * 32 + r] = acc;
  }
}

// ---------------------------------------------------------------------------
// K4: per-node online softmax over w(e)=S[n,ty]*S[tail,ty] + weighted gather.
// Round-7: half-wave per node (2 nodes/wave, float4 dims, chunk=32) --
// ~35% fewer wave-iterations + 5-stage butterflies (R6 structure lesson).
// ---------------------------------------------------------------------------
__global__ __launch_bounds__(256) void k_out2(
    const float* __restrict__ ent, const float* __restrict__ S,
    const int* __restrict__ off, const int2* __restrict__ teP,
    float* __restrict__ out) {
  const int t = threadIdx.x;
  const int wid = t >> 6;
  const int half = (t >> 5) & 1;
  const int l32 = t & 31;
  const int kk = wid * 2 + half;
  const int n = blockIdx.x * 8 + kk;
  if (n >= N_ENT) return;
  const int eb = off[n];
  const int deg = off[n + 1] - eb;
  float4 acc = {0, 0, 0, 0};
  float m = 0.f, ssum = 0.f;
  for (int b = 0; b < deg; b += 32) {
    const int idx = b + l32;
    const bool val = idx < deg;
    const int e = eb + (val ? idx : 0);
    const int2 tp = teP[e];
    const int tl = tp.x;
    const int ty = tp.y;
    float w = val ? S[(size_t)n * 32 + ty] * S[(size_t)tl * 32 + ty] : -1.f;
    float cm = w;
#pragma unroll
    for (int k = 1; k < 32; k <<= 1) cm = fmaxf(cm, __shfl_xor(cm, k));
    const float mnew = fmaxf(m, cm);
    const float scale = __expf(m - mnew);
    const float el = val ? __expf(w - mnew) : 0.f;
    float cs = el;
#pragma unroll
    for (int k = 1; k < 32; k <<= 1) cs += __shfl_xor(cs, k);
    ssum = ssum * scale + cs;
    acc.x *= scale; acc.y *= scale; acc.z *= scale; acc.w *= scale;
    const int cnt = (deg - b < 32) ? deg - b : 32;
    {
      const int tl0 = __shfl(tl, 0, 32);
      float4 xr = *(const float4*)&ent[(size_t)tl0 * D + l32 * 4];
      for (int j = 0; j < cnt; ++j) {
        const float sj = __shfl(el, j, 32);
        const float4 cx = xr;
        if (j + 1 < cnt) {
          const int tlj = __shfl(tl, j + 1, 32);
          xr = *(const float4*)&ent[(size_t)tlj * D + l32 * 4];
        }
        acc.x = fmaf(sj, cx.x, acc.x);
        acc.y = fmaf(sj, cx.y, acc.y);
        acc.z = fmaf(sj, cx.z, acc.z);
        acc.w = fmaf(sj, cx.w, acc.w);
      }
    }
    m = mnew;
  }
  const float inv = (deg > 0) ? 1.f / ssum : 0.f;
  float4 o = {acc.x * inv, acc.y * inv, acc.z * inv, acc.w * inv};
  *(float4*)&out[(size_t)n * D + l32 * 4] = o;
}

// ---------------------------------------------------------------------------
// Workspace (byte-identical footprint to the proven round-2 layout):
//   S [N*32] fp32; off[N+2], cur[N], deg[N], bsum/bbase[SCAN_NB] int;
//   teP [E] int2; kTt [128*128] fp32. wrel2 ALIASES cur (dead after scatter).
// d_out timeline: Q (k_qproj) -> consumed by k_fused -> output (k_out2).
// ---------------------------------------------------------------------------
extern "C" void kernel_launch(void* const* d_in, const int* in_sizes, int n_in,
                              void* d_out, int out_size, void* d_ws,
                              size_t ws_size, hipStream_t stream) {
  const float* ent = (const float*)d_in[0];
  const float* wrel = (const float*)d_in[3];
  const float* qT = (const float*)d_in[4];
  const float* kT = (const float*)d_in[5];
  const float* vT = (const float*)d_in[6];
  const int* eidx = (const int*)d_in[7];
  const int* etype = (const int*)d_in[8];
  const int* head = eidx;
  const int* tail = eidx + N_EDGE;

  float* S = (float*)d_ws;
  int* off = (int*)(S + (size_t)N_ENT * 32);
  int* cur = off + (N_ENT + 2);  // +2 keeps teP 8-byte aligned
  int* deg = cur + N_ENT;
  int* bsum = deg + N_ENT;
  int* bbase = bsum + SCAN_NB;
  int2* teP = (int2*)(bbase + SCAN_NB);
  float* kTt = (float*)(teP + N_EDGE);
  float* wrel2 = (float*)cur;  // 16 KB of the 400 KB dead cursor array
  float* qkg = (float*)d_out;

  hipMemsetAsync(deg, 0, N_ENT * sizeof(int), stream);
  k_hist<<<(N_EDGE + 255) / 256, 256, 0, stream>>>(head, deg);
  k_scan1<<<SCAN_NB, 256, 0, stream>>>(deg, bsum);
  k_scan2<<<1, 256, 0, stream>>>(bsum, bbase, off);
  k_scan3<<<SCAN_NB, 256, 0, stream>>>(deg, bbase, off, cur);
  k_scatter<<<(N_EDGE + 255) / 256, 256, 0, stream>>>(head, tail, etype, cur,
                                                      teP);
  k_prep<<<17, 256, 0, stream>>>(kT, kTt, wrel, wrel2);
  k_qproj<<<(N_ENT + 127) / 128, 512, 0, stream>>>(ent, qT, qkg);
  k_fused<<<N_ENT / 8, 256, 0, stream>>>(ent, wrel, kTt, vT, wrel2, qkg, S,
                                         off, teP);
  k_out2<<<(N_ENT + 7) / 8, 256, 0, stream>>>(ent, S, off, teP, qkg);
}

// Round 8
// 575.652 us; speedup vs baseline: 1.1084x; 1.1084x over previous
//
#include <hip/hip_runtime.h>
#include <cstdint>

#define D 128
#define H 4
#define N_ENT 100000
#define N_EDGE 400000
#define R 32

#define SCAN_NB ((N_ENT + 511) / 512)  // 196 blocks of 512 elements

// ---------------------------------------------------------------------------
// CSR build: histogram -> hierarchical scan -> scatter (permuted packed
// (tail,etype) int2).
// ---------------------------------------------------------------------------
__global__ void k_hist(const int* __restrict__ head, int* __restrict__ deg) {
  const int e = blockIdx.x * 256 + threadIdx.x;
  if (e < N_EDGE) atomicAdd(&deg[head[e]], 1);
}

__global__ __launch_bounds__(256) void k_scan1(const int* __restrict__ deg,
                                               int* __restrict__ bsum) {
  const int t = threadIdx.x;
  const int i = blockIdx.x * 512 + t * 2;
  int v0 = (i < N_ENT) ? deg[i] : 0;
  int v1 = (i + 1 < N_ENT) ? deg[i + 1] : 0;
  int s = v0 + v1;
#pragma unroll
  for (int k = 1; k < 64; k <<= 1) s += __shfl_xor(s, k);
  __shared__ int ws[4];
  if ((t & 63) == 0) ws[t >> 6] = s;
  __syncthreads();
  if (t == 0) bsum[blockIdx.x] = ws[0] + ws[1] + ws[2] + ws[3];
}

__global__ __launch_bounds__(256) void k_scan2(const int* __restrict__ bsum,
                                               int* __restrict__ bbase,
                                               int* __restrict__ off) {
  __shared__ int sh[256];
  const int t = threadIdx.x;
  const int v = (t < SCAN_NB) ? bsum[t] : 0;
  sh[t] = v;
  __syncthreads();
  for (int d = 1; d < 256; d <<= 1) {
    const int u = (t >= d) ? sh[t - d] : 0;
    __syncthreads();
    sh[t] += u;
    __syncthreads();
  }
  if (t < SCAN_NB) bbase[t] = sh[t] - v;
  if (t == SCAN_NB - 1) off[N_ENT] = sh[t];
}

__global__ __launch_bounds__(256) void k_scan3(const int* __restrict__ deg,
                                               const int* __restrict__ bbase,
                                               int* __restrict__ off,
                                               int* __restrict__ cur) {
  __shared__ int sh[256];
  const int t = threadIdx.x;
  const int i = blockIdx.x * 512 + t * 2;
  const int v0 = (i < N_ENT) ? deg[i] : 0;
  const int v1 = (i + 1 < N_ENT) ? deg[i + 1] : 0;
  const int s = v0 + v1;
  sh[t] = s;
  __syncthreads();
  for (int d = 1; d < 256; d <<= 1) {
    const int u = (t >= d) ? sh[t - d] : 0;
    __syncthreads();
    sh[t] += u;
    __syncthreads();
  }
  const int ex = sh[t] - s + bbase[blockIdx.x];
  if (i < N_ENT) {
    off[i] = ex;
    cur[i] = ex;
  }
  if (i + 1 < N_ENT) {
    off[i + 1] = ex + v0;
    cur[i + 1] = ex + v0;
  }
}

__global__ void k_scatter(const int* __restrict__ head,
                          const int* __restrict__ tail,
                          const int* __restrict__ etype, int* __restrict__ cur,
                          int2* __restrict__ teP) {
  const int e = blockIdx.x * 256 + threadIdx.x;
  if (e >= N_EDGE) return;
  const int hd = head[e];
  const int pos = atomicAdd(&cur[hd], 1);
  teP[pos] = make_int2(tail[e], etype[e] - 1);
}

// ---------------------------------------------------------------------------
// k_prep: blocks 0-15: kTt[j*128+i] = kT[i*128+j]; block 16: wrel2 = wrel^2.
// Runs AFTER k_scatter: wrel2 aliases the dead `cur` array.
// ---------------------------------------------------------------------------
__global__ __launch_bounds__(256) void k_prep(const float* __restrict__ kT,
                                              float* __restrict__ kTt,
                                              const float* __restrict__ wrel,
                                              float* __restrict__ wrel2) {
  if (blockIdx.x < 16) {
    __shared__ float tile[32][33];
    const int bx = blockIdx.x & 3, by = blockIdx.x >> 2;
    const int c = threadIdx.x & 31;
    const int r0 = (threadIdx.x >> 5) * 4;
#pragma unroll
    for (int i = 0; i < 4; ++i)
      tile[r0 + i][c] = kT[(by * 32 + r0 + i) * 128 + bx * 32 + c];
    __syncthreads();
#pragma unroll
    for (int i = 0; i < 4; ++i)
      kTt[(bx * 32 + r0 + i) * 128 + by * 32 + c] = tile[c][r0 + i];
  } else {
    const int t = threadIdx.x;
#pragma unroll
    for (int s = 0; s < 4; ++s) {
      const int idx = (s * 256 + t) * 4;
      float4 v = *(const float4*)&wrel[idx];
      v.x *= v.x; v.y *= v.y; v.z *= v.z; v.w *= v.w;
      *(float4*)&wrel2[idx] = v;
    }
  }
}

// ---------------------------------------------------------------------------
// K1: Q = entity_emb @ qTrans   (Q in d_out; consumed & overwritten later)
// ---------------------------------------------------------------------------
__global__ __launch_bounds__(512) void k_qproj(const float* __restrict__ ent,
                                               const float* __restrict__ qT,
                                               float* __restrict__ Q) {
  __shared__ float sT[D * D];
  __shared__ float rows[D * 128];
  const int t = threadIdx.x;
  const int n0 = blockIdx.x * 128;
#pragma unroll
  for (int s = 0; s < 8; ++s) {
    const int idx = (s * 512 + t) * 4;
    *(float4*)&sT[idx] = *(const float4*)&qT[idx];
  }
  {
    const int g = t & 3;
    const int n = t >> 2;
    const int node = n0 + n;
    if (node < N_ENT) {
      const float* src = ent + (size_t)node * D;
#pragma unroll
      for (int s = 0; s < 8; ++s) {
        const int i = s * 16 + g * 4;
        float4 v = *(const float4*)&src[i];
        rows[(i + 0) * 128 + n] = v.x;
        rows[(i + 1) * 128 + n] = v.y;
        rows[(i + 2) * 128 + n] = v.z;
        rows[(i + 3) * 128 + n] = v.w;
      }
    } else {
#pragma unroll
      for (int s = 0; s < 8; ++s) {
        const int i = s * 16 + g * 4;
        rows[(i + 0) * 128 + n] = 0.f;
        rows[(i + 1) * 128 + n] = 0.f;
        rows[(i + 2) * 128 + n] = 0.f;
        rows[(i + 3) * 128 + n] = 0.f;
      }
    }
  }
  __syncthreads();
  const int jj = t & 15;
  const int ee = t >> 4;
  float acc[4][8];
#pragma unroll
  for (int a = 0; a < 4; ++a)
#pragma unroll
    for (int b = 0; b < 8; ++b) acc[a][b] = 0.f;
#pragma unroll 4
  for (int i = 0; i < D; ++i) {
    float4 b0 = *(float4*)&sT[i * D + jj * 8];
    float4 b1 = *(float4*)&sT[i * D + jj * 8 + 4];
    float4 a0 = *(float4*)&rows[i * 128 + ee * 4];
    float bv[8] = {b0.x, b0.y, b0.z, b0.w, b1.x, b1.y, b1.z, b1.w};
    float av[4] = {a0.x, a0.y, a0.z, a0.w};
#pragma unroll
    for (int a = 0; a < 4; ++a)
#pragma unroll
      for (int b = 0; b < 8; ++b) acc[a][b] = fmaf(av[a], bv[b], acc[a][b]);
  }
#pragma unroll
  for (int a = 0; a < 4; ++a) {
    const int node = n0 + ee * 4 + a;
    if (node < N_ENT) {
      float4 o0 = {acc[a][0], acc[a][1], acc[a][2], acc[a][3]};
      float4 o1 = {acc[a][4], acc[a][5], acc[a][6], acc[a][7]};
      *(float4*)&Q[(size_t)node * D + jj * 8] = o0;
      *(float4*)&Q[(size_t)node * D + jj * 8 + 4] = o1;
    }
  }
}

// ---------------------------------------------------------------------------
// K2: fused attention + S. 256 threads, 8 nodes/block (one node per 32-lane
// HALF-WAVE, float4 per lane), 20 KB LDS, (256,4) = VGPR 64, NO spills.
// Structure = R1's proven 253us edge loop (P in registers) + fused P3/P4
// tail (kg never hits HBM) + DEPTH-2 edge prefetch: two (xv,rv) register
// sets, both first-edge gathers issued before P1 so two gathers are always
// in flight (avg deg = 4 -> depth-1 left ~deg x 500cy of exposed latency).
// R7 lesson: ds_read-P + clamp-32 spilled accumulators (218MB scratch).
// R2 lesson: clamp-32 spills bought occupancy but only +8% vs R1.
// ---------------------------------------------------------------------------
__global__ __launch_bounds__(256, 4) void k_fused(
    const float* __restrict__ ent, const float* __restrict__ wrel,
    const float* __restrict__ kTt, const float* __restrict__ vT,
    const float* __restrict__ wrel2, const float* __restrict__ qkg,
    float* __restrict__ S, const int* __restrict__ off,
    const int2* __restrict__ teP) {
  __shared__ float sQ[8 * 128];    //  4 KB: Q, later kg^2
  __shared__ float sPA[8 * 512];   // 16 KB: P, then Agg (lane-private alias)
  const int t = threadIdx.x;
  const int base = blockIdx.x * 8;
  const int wid = t >> 6;
  const int half = (t >> 5) & 1;
  const int l32 = t & 31;
  const int kk = wid * 2 + half;
  const int n = base + kk;

  // P0: stage Q rows (8 x 128 floats, one float4 per thread)
  {
    const int k = t >> 5;
    const int c4 = (t & 31) * 4;
    *(float4*)&sQ[k * 128 + c4] =
        *(const float4*)&qkg[(size_t)(base + k) * D + c4];
  }

  // hoisted: CSR range + first TWO edge gathers (latency overlaps P1)
  const int eb = off[n];
  const int deg = off[n + 1] - eb;
  float4 xv0 = {0, 0, 0, 0}, rv0 = {0, 0, 0, 0};
  float4 xv1 = {0, 0, 0, 0}, rv1 = {0, 0, 0, 0};
  if (deg > 0) {
    const int2 pf = teP[eb];
    xv0 = *(const float4*)&ent[(size_t)pf.x * D + l32 * 4];
    rv0 = *(const float4*)&wrel[(size_t)pf.y * D + l32 * 4];
  }
  if (deg > 1) {
    const int2 pf = teP[eb + 1];
    xv1 = *(const float4*)&ent[(size_t)pf.x * D + l32 * 4];
    rv1 = *(const float4*)&wrel[(size_t)pf.y * D + l32 * 4];
  }
  __syncthreads();

  // P1: P[k,h,i] = sum_c kTt[h*32+c, i] * Q[k, h*32+c] -> sPA.
  {
    const int i = t & 127;
    const int sub = t >> 7;
    float pp[2][8];
#pragma unroll
    for (int hh = 0; hh < 2; ++hh)
#pragma unroll
      for (int k = 0; k < 8; ++k) pp[hh][k] = 0.f;
#pragma unroll
    for (int hh = 0; hh < 2; ++hh) {
      const int h = sub * 2 + hh;
#pragma unroll 2
      for (int c4 = 0; c4 < 8; ++c4) {
        const float kv0 = kTt[(h * 32 + c4 * 4 + 0) * 128 + i];
        const float kv1 = kTt[(h * 32 + c4 * 4 + 1) * 128 + i];
        const float kv2 = kTt[(h * 32 + c4 * 4 + 2) * 128 + i];
        const float kv3 = kTt[(h * 32 + c4 * 4 + 3) * 128 + i];
#pragma unroll
        for (int k = 0; k < 8; ++k) {
          const float4 q = *(const float4*)&sQ[k * 128 + h * 32 + c4 * 4];
          pp[hh][k] = fmaf(kv0, q.x, pp[hh][k]);
          pp[hh][k] = fmaf(kv1, q.y, pp[hh][k]);
          pp[hh][k] = fmaf(kv2, q.z, pp[hh][k]);
          pp[hh][k] = fmaf(kv3, q.w, pp[hh][k]);
        }
      }
    }
#pragma unroll
    for (int hh = 0; hh < 2; ++hh)
#pragma unroll
      for (int k = 0; k < 8; ++k)
        sPA[k * 512 + (sub * 2 + hh) * 128 + i] = pp[hh][k];
  }
  __syncthreads();

  // P2: edge loop. half-wave owns one node; P in 16 registers (R1-proven).
  // lane lp = l32&3 carries head (lp^m) in accumulator b_m.
  {
    const int lp = l32 & 3;
    const float4 P0 = *(const float4*)&sPA[kk * 512 + 0 * 128 + l32 * 4];
    const float4 P1 = *(const float4*)&sPA[kk * 512 + 1 * 128 + l32 * 4];
    const float4 P2 = *(const float4*)&sPA[kk * 512 + 2 * 128 + l32 * 4];
    const float4 P3 = *(const float4*)&sPA[kk * 512 + 3 * 128 + l32 * 4];
    float4 b0 = {0, 0, 0, 0}, b1 = {0, 0, 0, 0};
    float4 b2 = {0, 0, 0, 0}, b3 = {0, 0, 0, 0};
    float s0 = 0.f, s1 = 0.f, s2 = 0.f, s3 = 0.f;
    for (int idx = 0; idx < deg; ++idx) {
      const float4 nh = {xv0.x * rv0.x, xv0.y * rv0.y, xv0.z * rv0.z,
                         xv0.w * rv0.w};
      xv0 = xv1;
      rv0 = rv1;
      if (idx + 2 < deg) {
        const int2 pf = teP[eb + idx + 2];
        xv1 = *(const float4*)&ent[(size_t)pf.x * D + l32 * 4];
        rv1 = *(const float4*)&wrel[(size_t)pf.y * D + l32 * 4];
      }
      float d0 = nh.x * P0.x + nh.y * P0.y + nh.z * P0.z + nh.w * P0.w;
      float d1 = nh.x * P1.x + nh.y * P1.y + nh.z * P1.z + nh.w * P1.w;
      float d2 = nh.x * P2.x + nh.y * P2.y + nh.z * P2.z + nh.w * P2.w;
      float d3 = nh.x * P3.x + nh.y * P3.y + nh.z * P3.z + nh.w * P3.w;
      // packed 4-value butterfly: lane ends with full sum of d_{l32&3}
      float x01 = (l32 & 1) ? d1 : d0;
      float y01 = (l32 & 1) ? d0 : d1;
      x01 += __shfl_xor(y01, 1);
      float x23 = (l32 & 1) ? d3 : d2;
      float y23 = (l32 & 1) ? d2 : d3;
      x23 += __shfl_xor(y23, 1);
      float xa = (l32 & 2) ? x23 : x01;
      float xb = (l32 & 2) ? x01 : x23;
      xa += __shfl_xor(xb, 2);
      xa += __shfl_xor(xa, 4);
      xa += __shfl_xor(xa, 8);
      xa += __shfl_xor(xa, 16);
      const float eL = __expf(fminf(fmaxf(xa, -10.f), 10.f));
      const float e0 = eL;                 // head lp
      const float e1 = __shfl_xor(eL, 1);  // head lp^1
      const float e2 = __shfl_xor(eL, 2);  // head lp^2
      const float e3 = __shfl_xor(eL, 3);  // head lp^3
      b0.x = fmaf(e0, nh.x, b0.x); b0.y = fmaf(e0, nh.y, b0.y);
      b0.z = fmaf(e0, nh.z, b0.z); b0.w = fmaf(e0, nh.w, b0.w);
      b1.x = fmaf(e1, nh.x, b1.x); b1.y = fmaf(e1, nh.y, b1.y);
      b1.z = fmaf(e1, nh.z, b1.z); b1.w = fmaf(e1, nh.w, b1.w);
      b2.x = fmaf(e2, nh.x, b2.x); b2.y = fmaf(e2, nh.y, b2.y);
      b2.z = fmaf(e2, nh.z, b2.z); b2.w = fmaf(e2, nh.w, b2.w);
      b3.x = fmaf(e3, nh.x, b3.x); b3.y = fmaf(e3, nh.y, b3.y);
      b3.z = fmaf(e3, nh.z, b3.z); b3.w = fmaf(e3, nh.w, b3.w);
      s0 += e0; s1 += e1; s2 += e2; s3 += e3;
    }
    const float i0 = 1.f / (s0 + 1e-8f);
    const float i1 = 1.f / (s1 + 1e-8f);
    const float i2 = 1.f / (s2 + 1e-8f);
    const float i3 = 1.f / (s3 + 1e-8f);
    float4 o0 = {b0.x * i0, b0.y * i0, b0.z * i0, b0.w * i0};
    float4 o1 = {b1.x * i1, b1.y * i1, b1.z * i1, b1.w * i1};
    float4 o2 = {b2.x * i2, b2.y * i2, b2.z * i2, b2.w * i2};
    float4 o3 = {b3.x * i3, b3.y * i3, b3.z * i3, b3.w * i3};
    const int sb = kk * 512 + l32 * 4;
    *(float4*)&sPA[sb + ((lp ^ 0) << 7)] = o0;
    *(float4*)&sPA[sb + ((lp ^ 1) << 7)] = o1;
    *(float4*)&sPA[sb + ((lp ^ 2) << 7)] = o2;
    *(float4*)&sPA[sb + ((lp ^ 3) << 7)] = o3;
  }
  __syncthreads();

  // P3: kg[n,c] = sum_d agg[n,h(c),d]*vT[d,c] (regs); kg^2 -> sQ (Q dead).
  {
    const int c = t & 127;
    const int g4 = (t >> 7) * 4;
    const int h = c >> 5;
    float acc0 = 0.f, acc1 = 0.f, acc2 = 0.f, acc3 = 0.f;
    const float* agg0 = &sPA[(g4 + 0) * 512 + h * 128];
    const float* agg1 = &sPA[(g4 + 1) * 512 + h * 128];
    const float* agg2 = &sPA[(g4 + 2) * 512 + h * 128];
    const float* agg3 = &sPA[(g4 + 3) * 512 + h * 128];
#pragma unroll 4
    for (int d4 = 0; d4 < 32; ++d4) {
      const float4 a0 = *(const float4*)&agg0[d4 * 4];
      const float4 a1 = *(const float4*)&agg1[d4 * 4];
      const float4 a2 = *(const float4*)&agg2[d4 * 4];
      const float4 a3 = *(const float4*)&agg3[d4 * 4];
      const float v0 = vT[(d4 * 4 + 0) * 128 + c];
      const float v1 = vT[(d4 * 4 + 1) * 128 + c];
      const float v2 = vT[(d4 * 4 + 2) * 128 + c];
      const float v3 = vT[(d4 * 4 + 3) * 128 + c];
      acc0 = fmaf(a0.x, v0, acc0); acc0 = fmaf(a0.y, v1, acc0);
      acc0 = fmaf(a0.z, v2, acc0); acc0 = fmaf(a0.w, v3, acc0);
      acc1 = fmaf(a1.x, v0, acc1); acc1 = fmaf(a1.y, v1, acc1);
      acc1 = fmaf(a1.z, v2, acc1); acc1 = fmaf(a1.w, v3, acc1);
      acc2 = fmaf(a2.x, v0, acc2); acc2 = fmaf(a2.y, v1, acc2);
      acc2 = fmaf(a2.z, v2, acc2); acc2 = fmaf(a2.w, v3, acc2);
      acc3 = fmaf(a3.x, v0, acc3); acc3 = fmaf(a3.y, v1, acc3);
      acc3 = fmaf(a3.z, v2, acc3); acc3 = fmaf(a3.w, v3, acc3);
    }
    sQ[(g4 + 0) * 128 + c] = acc0 * acc0;
    sQ[(g4 + 1) * 128 + c] = acc1 * acc1;
    sQ[(g4 + 2) * 128 + c] = acc2 * acc2;
    sQ[(g4 + 3) * 128 + c] = acc3 * acc3;
  }
  __syncthreads();

  // P4: S[n,r] = sum_c kg2[n,c] * wrel2[r,c]; coalesced store.
  {
    const int nn = t >> 5;  // 0..7
    const int r = t & 31;
    const float* kg2 = &sQ[nn * 128];
    const float* w2 = &wrel2[r * 128];
    float acc = 0.f;
#pragma unroll 4
    for (int c4 = 0; c4 < 32; ++c4) {
      const float4 a = *(const float4*)&kg2[c4 * 4];
      const float4 b = *(const float4*)&w2[c4 * 4];
      acc = fmaf(a.x, b.x, acc); acc = fmaf(a.y, b.y, acc);
      acc = fmaf(a.z, b.z, acc); acc = fmaf(a.w, b.w, acc);
    }
    S[(size_t)(base + nn) * 32 + r] = acc;
  }
}

// ---------------------------------------------------------------------------
// K4: per-node softmax over w(e)=S[n,ty]*S[tail,ty] + weighted gather.
// Round-8 restructure (was ~150us hidden cost; serial depth-1 row loads):
//   - S[n] row preloaded into ONE lane register; per-edge S[n][ty] becomes a
//     __shfl instead of a gather.
//   - aggregation loop processes 4 edges per group with 4 INDEPENDENT row
//     loads in flight (no rescale inside a chunk -> loads independent);
//     exposed latency ~ceil(deg/4) x 500cy instead of deg x 500cy.
// Half-wave per node (2 nodes/wave), float4 dims, chunk=32.
// ---------------------------------------------------------------------------
__global__ __launch_bounds__(256) void k_out2(
    const float* __restrict__ ent, const float* __restrict__ S,
    const int* __restrict__ off, const int2* __restrict__ teP,
    float* __restrict__ out) {
  const int t = threadIdx.x;
  const int wid = t >> 6;
  const int half = (t >> 5) & 1;
  const int l32 = t & 31;
  const int kk = wid * 2 + half;
  const int n = blockIdx.x * 8 + kk;
  if (n >= N_ENT) return;
  const int eb = off[n];
  const int deg = off[n + 1] - eb;
  const float sn = S[(size_t)n * 32 + l32];  // lane l holds S[n][l]
  float4 acc = {0, 0, 0, 0};
  float m = 0.f, ssum = 0.f;
  for (int b = 0; b < deg; b += 32) {
    const int idx = b + l32;
    const bool val = idx < deg;
    const int e = eb + (val ? idx : 0);
    const int2 tp = teP[e];
    const int tl = tp.x;
    const int ty = tp.y;
    const float snv = __shfl(sn, ty, 32);
    float w = val ? snv * S[(size_t)tl * 32 + ty] : -1.f;
    float cm = w;
#pragma unroll
    for (int k = 1; k < 32; k <<= 1) cm = fmaxf(cm, __shfl_xor(cm, k));
    const float mnew = fmaxf(m, cm);
    const float scale = __expf(m - mnew);
    const float el = val ? __expf(w - mnew) : 0.f;
    float cs = el;
#pragma unroll
    for (int k = 1; k < 32; k <<= 1) cs += __shfl_xor(cs, k);
    ssum = ssum * scale + cs;
    acc.x *= scale; acc.y *= scale; acc.z *= scale; acc.w *= scale;
    const int cnt = (deg - b < 32) ? deg - b : 32;
    for (int j0 = 0; j0 < cnt; j0 += 4) {
      const int rem = cnt - j0;
      // issue up to 4 independent row loads back-to-back (MLP = 4)
      const int t0 = __shfl(tl, j0 + 0, 32);
      float4 r0 = *(const float4*)&ent[(size_t)t0 * D + l32 * 4];
      float4 r1, r2, r3;
      if (rem > 1) {
        const int t1 = __shfl(tl, j0 + 1, 32);
        r1 = *(const float4*)&ent[(size_t)t1 * D + l32 * 4];
      }
      if (rem > 2) {
        const int t2 = __shfl(tl, j0 + 2, 32);
        r2 = *(const float4*)&ent[(size_t)t2 * D + l32 * 4];
      }
      if (rem > 3) {
        const int t3 = __shfl(tl, j0 + 3, 32);
        r3 = *(const float4*)&ent[(size_t)t3 * D + l32 * 4];
      }
      const float w0 = __shfl(el, j0 + 0, 32);
      acc.x = fmaf(w0, r0.x, acc.x); acc.y = fmaf(w0, r0.y, acc.y);
      acc.z = fmaf(w0, r0.z, acc.z); acc.w = fmaf(w0, r0.w, acc.w);
      if (rem > 1) {
        const float w1 = __shfl(el, j0 + 1, 32);
        acc.x = fmaf(w1, r1.x, acc.x); acc.y = fmaf(w1, r1.y, acc.y);
        acc.z = fmaf(w1, r1.z, acc.z); acc.w = fmaf(w1, r1.w, acc.w);
      }
      if (rem > 2) {
        const float w2 = __shfl(el, j0 + 2, 32);
        acc.x = fmaf(w2, r2.x, acc.x); acc.y = fmaf(w2, r2.y, acc.y);
        acc.z = fmaf(w2, r2.z, acc.z); acc.w = fmaf(w2, r2.w, acc.w);
      }
      if (rem > 3) {
        const float w3 = __shfl(el, j0 + 3, 32);
        acc.x = fmaf(w3, r3.x, acc.x); acc.y = fmaf(w3, r3.y, acc.y);
        acc.z = fmaf(w3, r3.z, acc.z); acc.w = fmaf(w3, r3.w, acc.w);
      }
    }
    m = mnew;
  }
  const float inv = (deg > 0) ? 1.f / ssum : 0.f;
  float4 o = {acc.x * inv, acc.y * inv, acc.z * inv, acc.w * inv};
  *(float4*)&out[(size_t)n * D + l32 * 4] = o;
}

// ---------------------------------------------------------------------------
// Workspace (byte-identical footprint to the proven round-2 layout):
//   S [N*32] fp32; off[N+2], cur[N], deg[N], bsum/bbase[SCAN_NB] int;
//   teP [E] int2; kTt [128*128] fp32. wrel2 ALIASES cur (dead after scatter).
// d_out timeline: Q (k_qproj) -> consumed by k_fused -> output (k_out2).
// ---------------------------------------------------------------------------
extern "C" void kernel_launch(void* const* d_in, const int* in_sizes, int n_in,
                              void* d_out, int out_size, void* d_ws,
                              size_t ws_size, hipStream_t stream) {
  const float* ent = (const float*)d_in[0];
  const float* wrel = (const float*)d_in[3];
  const float* qT = (const float*)d_in[4];
  const float* kT = (const float*)d_in[5];
  const float* vT = (const float*)d_in[6];
  const int* eidx = (const int*)d_in[7];
  const int* etype = (const int*)d_in[8];
  const int* head = eidx;
  const int* tail = eidx + N_EDGE;

  float* S = (float*)d_ws;
  int* off = (int*)(S + (size_t)N_ENT * 32);
  int* cur = off + (N_ENT + 2);  // +2 keeps teP 8-byte aligned
  int* deg = cur + N_ENT;
  int* bsum = deg + N_ENT;
  int* bbase = bsum + SCAN_NB;
  int2* teP = (int2*)(bbase + SCAN_NB);
  float* kTt = (float*)(teP + N_EDGE);
  float* wrel2 = (float*)cur;  // 16 KB of the 400 KB dead cursor array
  float* qkg = (float*)d_out;

  hipMemsetAsync(deg, 0, N_ENT * sizeof(int), stream);
  k_hist<<<(N_EDGE + 255) / 256, 256, 0, stream>>>(head, deg);
  k_scan1<<<SCAN_NB, 256, 0, stream>>>(deg, bsum);
  k_scan2<<<1, 256, 0, stream>>>(bsum, bbase, off);
  k_scan3<<<SCAN_NB, 256, 0, stream>>>(deg, bbase, off, cur);
  k_scatter<<<(N_EDGE + 255) / 256, 256, 0, stream>>>(head, tail, etype, cur,
                                                      teP);
  k_prep<<<17, 256, 0, stream>>>(kT, kTt, wrel, wrel2);
  k_qproj<<<(N_ENT + 127) / 128, 512, 0, stream>>>(ent, qT, qkg);
  k_fused<<<N_ENT / 8, 256, 0, stream>>>(ent, wrel, kTt, vT, wrel2, qkg, S,
                                         off, teP);
  k_out2<<<(N_ENT + 7) / 8, 256, 0, stream>>>(ent, S, off, teP, qkg);
}

// Round 9
// 554.193 us; speedup vs baseline: 1.1513x; 1.0387x over previous
//
#include <hip/hip_runtime.h>
#include <cstdint>

#define D 128
#define H 4
#define N_ENT 100000
#define N_EDGE 400000
#define R 32

#define SCAN_NB ((N_ENT + 511) / 512)  // 196 blocks of 512 elements

// ---------------------------------------------------------------------------
// CSR build: histogram -> hierarchical scan -> scatter (permuted packed
// (tail,etype) int2).
// ---------------------------------------------------------------------------
__global__ void k_hist(const int* __restrict__ head, int* __restrict__ deg) {
  const int e = blockIdx.x * 256 + threadIdx.x;
  if (e < N_EDGE) atomicAdd(&deg[head[e]], 1);
}

__global__ __launch_bounds__(256) void k_scan1(const int* __restrict__ deg,
                                               int* __restrict__ bsum) {
  const int t = threadIdx.x;
  const int i = blockIdx.x * 512 + t * 2;
  int v0 = (i < N_ENT) ? deg[i] : 0;
  int v1 = (i + 1 < N_ENT) ? deg[i + 1] : 0;
  int s = v0 + v1;
#pragma unroll
  for (int k = 1; k < 64; k <<= 1) s += __shfl_xor(s, k);
  __shared__ int ws[4];
  if ((t & 63) == 0) ws[t >> 6] = s;
  __syncthreads();
  if (t == 0) bsum[blockIdx.x] = ws[0] + ws[1] + ws[2] + ws[3];
}

__global__ __launch_bounds__(256) void k_scan2(const int* __restrict__ bsum,
                                               int* __restrict__ bbase,
                                               int* __restrict__ off) {
  __shared__ int sh[256];
  const int t = threadIdx.x;
  const int v = (t < SCAN_NB) ? bsum[t] : 0;
  sh[t] = v;
  __syncthreads();
  for (int d = 1; d < 256; d <<= 1) {
    const int u = (t >= d) ? sh[t - d] : 0;
    __syncthreads();
    sh[t] += u;
    __syncthreads();
  }
  if (t < SCAN_NB) bbase[t] = sh[t] - v;
  if (t == SCAN_NB - 1) off[N_ENT] = sh[t];
}

__global__ __launch_bounds__(256) void k_scan3(const int* __restrict__ deg,
                                               const int* __restrict__ bbase,
                                               int* __restrict__ off,
                                               int* __restrict__ cur) {
  __shared__ int sh[256];
  const int t = threadIdx.x;
  const int i = blockIdx.x * 512 + t * 2;
  const int v0 = (i < N_ENT) ? deg[i] : 0;
  const int v1 = (i + 1 < N_ENT) ? deg[i + 1] : 0;
  const int s = v0 + v1;
  sh[t] = s;
  __syncthreads();
  for (int d = 1; d < 256; d <<= 1) {
    const int u = (t >= d) ? sh[t - d] : 0;
    __syncthreads();
    sh[t] += u;
    __syncthreads();
  }
  const int ex = sh[t] - s + bbase[blockIdx.x];
  if (i < N_ENT) {
    off[i] = ex;
    cur[i] = ex;
  }
  if (i + 1 < N_ENT) {
    off[i + 1] = ex + v0;
    cur[i + 1] = ex + v0;
  }
}

__global__ void k_scatter(const int* __restrict__ head,
                          const int* __restrict__ tail,
                          const int* __restrict__ etype, int* __restrict__ cur,
                          int2* __restrict__ teP) {
  const int e = blockIdx.x * 256 + threadIdx.x;
  if (e >= N_EDGE) return;
  const int hd = head[e];
  const int pos = atomicAdd(&cur[hd], 1);
  teP[pos] = make_int2(tail[e], etype[e] - 1);
}

// ---------------------------------------------------------------------------
// k_prep: blocks 0-15: kTt[j*128+i] = kT[i*128+j]; block 16: wrel2 = wrel^2.
// Runs AFTER k_scatter: wrel2 aliases the dead `cur` array.
// ---------------------------------------------------------------------------
__global__ __launch_bounds__(256) void k_prep(const float* __restrict__ kT,
                                              float* __restrict__ kTt,
                                              const float* __restrict__ wrel,
                                              float* __restrict__ wrel2) {
  if (blockIdx.x < 16) {
    __shared__ float tile[32][33];
    const int bx = blockIdx.x & 3, by = blockIdx.x >> 2;
    const int c = threadIdx.x & 31;
    const int r0 = (threadIdx.x >> 5) * 4;
#pragma unroll
    for (int i = 0; i < 4; ++i)
      tile[r0 + i][c] = kT[(by * 32 + r0 + i) * 128 + bx * 32 + c];
    __syncthreads();
#pragma unroll
    for (int i = 0; i < 4; ++i)
      kTt[(bx * 32 + r0 + i) * 128 + by * 32 + c] = tile[c][r0 + i];
  } else {
    const int t = threadIdx.x;
#pragma unroll
    for (int s = 0; s < 4; ++s) {
      const int idx = (s * 256 + t) * 4;
      float4 v = *(const float4*)&wrel[idx];
      v.x *= v.x; v.y *= v.y; v.z *= v.z; v.w *= v.w;
      *(float4*)&wrel2[idx] = v;
    }
  }
}

// ---------------------------------------------------------------------------
// K1: Q = entity_emb @ qTrans   (Q in d_out; consumed & overwritten later)
// ---------------------------------------------------------------------------
__global__ __launch_bounds__(512) void k_qproj(const float* __restrict__ ent,
                                               const float* __restrict__ qT,
                                               float* __restrict__ Q) {
  __shared__ float sT[D * D];
  __shared__ float rows[D * 128];
  const int t = threadIdx.x;
  const int n0 = blockIdx.x * 128;
#pragma unroll
  for (int s = 0; s < 8; ++s) {
    const int idx = (s * 512 + t) * 4;
    *(float4*)&sT[idx] = *(const float4*)&qT[idx];
  }
  {
    const int g = t & 3;
    const int n = t >> 2;
    const int node = n0 + n;
    if (node < N_ENT) {
      const float* src = ent + (size_t)node * D;
#pragma unroll
      for (int s = 0; s < 8; ++s) {
        const int i = s * 16 + g * 4;
        float4 v = *(const float4*)&src[i];
        rows[(i + 0) * 128 + n] = v.x;
        rows[(i + 1) * 128 + n] = v.y;
        rows[(i + 2) * 128 + n] = v.z;
        rows[(i + 3) * 128 + n] = v.w;
      }
    } else {
#pragma unroll
      for (int s = 0; s < 8; ++s) {
        const int i = s * 16 + g * 4;
        rows[(i + 0) * 128 + n] = 0.f;
        rows[(i + 1) * 128 + n] = 0.f;
        rows[(i + 2) * 128 + n] = 0.f;
        rows[(i + 3) * 128 + n] = 0.f;
      }
    }
  }
  __syncthreads();
  const int jj = t & 15;
  const int ee = t >> 4;
  float acc[4][8];
#pragma unroll
  for (int a = 0; a < 4; ++a)
#pragma unroll
    for (int b = 0; b < 8; ++b) acc[a][b] = 0.f;
#pragma unroll 4
  for (int i = 0; i < D; ++i) {
    float4 b0 = *(float4*)&sT[i * D + jj * 8];
    float4 b1 = *(float4*)&sT[i * D + jj * 8 + 4];
    float4 a0 = *(float4*)&rows[i * 128 + ee * 4];
    float bv[8] = {b0.x, b0.y, b0.z, b0.w, b1.x, b1.y, b1.z, b1.w};
    float av[4] = {a0.x, a0.y, a0.z, a0.w};
#pragma unroll
    for (int a = 0; a < 4; ++a)
#pragma unroll
      for (int b = 0; b < 8; ++b) acc[a][b] = fmaf(av[a], bv[b], acc[a][b]);
  }
#pragma unroll
  for (int a = 0; a < 4; ++a) {
    const int node = n0 + ee * 4 + a;
    if (node < N_ENT) {
      float4 o0 = {acc[a][0], acc[a][1], acc[a][2], acc[a][3]};
      float4 o1 = {acc[a][4], acc[a][5], acc[a][6], acc[a][7]};
      *(float4*)&Q[(size_t)node * D + jj * 8] = o0;
      *(float4*)&Q[(size_t)node * D + jj * 8 + 4] = o1;
    }
  }
}

// ---------------------------------------------------------------------------
// K2: fused attention + S. 256 threads, 8 nodes/block (one node per 32-lane
// HALF-WAVE, float4 per lane), 36 KB LDS, (256,4) -> VGPR ~64, no spills.
// R8 lesson: depth-2 row prefetch (+16 VGPR) spilled (~22MB scratch) and
// regressed; revert to depth-1 rows.
// This round's chain fix (cheap):
//   - wrel staged in LDS (sW, 16 KB): per-edge rv becomes conflict-free
//     ds_read_b128 on the DS pipe; LDS 20->36 KB is free (VGPR=64 caps
//     occupancy at ~3.5 blocks/CU anyway).
//   - next-edge (tail,etype) int2 held in registers one iteration ahead
//     (+2 VGPR): row loads issue with a ready address, so teP latency and
//     row latency each get a full iteration of overlap (chain ~500->~300cy).
// ---------------------------------------------------------------------------
__global__ __launch_bounds__(256, 4) void k_fused(
    const float* __restrict__ ent, const float* __restrict__ wrel,
    const float* __restrict__ kTt, const float* __restrict__ vT,
    const float* __restrict__ wrel2, const float* __restrict__ qkg,
    float* __restrict__ S, const int* __restrict__ off,
    const int2* __restrict__ teP) {
  __shared__ float sQ[8 * 128];    //  4 KB: Q, later kg^2
  __shared__ float sPA[8 * 512];   // 16 KB: P, then Agg (lane-private alias)
  __shared__ float sW[R * D];      // 16 KB: wrel staged once per block
  const int t = threadIdx.x;
  const int base = blockIdx.x * 8;
  const int wid = t >> 6;
  const int half = (t >> 5) & 1;
  const int l32 = t & 31;
  const int kk = wid * 2 + half;
  const int n = base + kk;

  // P0: stage Q rows (8 x 128) + wrel (32 x 128)
  {
    const int k = t >> 5;
    const int c4 = (t & 31) * 4;
    *(float4*)&sQ[k * 128 + c4] =
        *(const float4*)&qkg[(size_t)(base + k) * D + c4];
#pragma unroll
    for (int s = 0; s < 4; ++s) {
      const int i4 = (s * 256 + t) * 4;
      *(float4*)&sW[i4] = *(const float4*)&wrel[i4];
    }
  }

  // hoisted: CSR range, edge-0 index + ent row, edge-1 index (overlaps P1)
  const int eb = off[n];
  const int deg = off[n + 1] - eb;
  int2 pfc = make_int2(0, 0), pfn = make_int2(0, 0);
  float4 xv = {0, 0, 0, 0};
  if (deg > 0) {
    pfc = teP[eb];
    xv = *(const float4*)&ent[(size_t)pfc.x * D + l32 * 4];
  }
  if (deg > 1) pfn = teP[eb + 1];
  __syncthreads();

  // P1: P[k,h,i] = sum_c kTt[h*32+c, i] * Q[k, h*32+c] -> sPA.
  {
    const int i = t & 127;
    const int sub = t >> 7;
    float pp[2][8];
#pragma unroll
    for (int hh = 0; hh < 2; ++hh)
#pragma unroll
      for (int k = 0; k < 8; ++k) pp[hh][k] = 0.f;
#pragma unroll
    for (int hh = 0; hh < 2; ++hh) {
      const int h = sub * 2 + hh;
#pragma unroll 2
      for (int c4 = 0; c4 < 8; ++c4) {
        const float kv0 = kTt[(h * 32 + c4 * 4 + 0) * 128 + i];
        const float kv1 = kTt[(h * 32 + c4 * 4 + 1) * 128 + i];
        const float kv2 = kTt[(h * 32 + c4 * 4 + 2) * 128 + i];
        const float kv3 = kTt[(h * 32 + c4 * 4 + 3) * 128 + i];
#pragma unroll
        for (int k = 0; k < 8; ++k) {
          const float4 q = *(const float4*)&sQ[k * 128 + h * 32 + c4 * 4];
          pp[hh][k] = fmaf(kv0, q.x, pp[hh][k]);
          pp[hh][k] = fmaf(kv1, q.y, pp[hh][k]);
          pp[hh][k] = fmaf(kv2, q.z, pp[hh][k]);
          pp[hh][k] = fmaf(kv3, q.w, pp[hh][k]);
        }
      }
    }
#pragma unroll
    for (int hh = 0; hh < 2; ++hh)
#pragma unroll
      for (int k = 0; k < 8; ++k)
        sPA[k * 512 + (sub * 2 + hh) * 128 + i] = pp[hh][k];
  }
  __syncthreads();

  // P2: edge loop. half-wave owns one node; P in 16 registers (R1-proven).
  // lane lp = l32&3 carries head (lp^m) in accumulator b_m.
  {
    const int lp = l32 & 3;
    const float4 P0 = *(const float4*)&sPA[kk * 512 + 0 * 128 + l32 * 4];
    const float4 P1 = *(const float4*)&sPA[kk * 512 + 1 * 128 + l32 * 4];
    const float4 P2 = *(const float4*)&sPA[kk * 512 + 2 * 128 + l32 * 4];
    const float4 P3 = *(const float4*)&sPA[kk * 512 + 3 * 128 + l32 * 4];
    float4 rv = {0, 0, 0, 0};
    if (deg > 0) rv = *(const float4*)&sW[pfc.y * 128 + l32 * 4];
    float4 b0 = {0, 0, 0, 0}, b1 = {0, 0, 0, 0};
    float4 b2 = {0, 0, 0, 0}, b3 = {0, 0, 0, 0};
    float s0 = 0.f, s1 = 0.f, s2 = 0.f, s3 = 0.f;
    for (int idx = 0; idx < deg; ++idx) {
      const float4 nh = {xv.x * rv.x, xv.y * rv.y, xv.z * rv.z, xv.w * rv.w};
      if (idx + 1 < deg) {
        // row loads for edge idx+1: address (pfn) already in registers
        xv = *(const float4*)&ent[(size_t)pfn.x * D + l32 * 4];
        rv = *(const float4*)&sW[pfn.y * 128 + l32 * 4];
      }
      if (idx + 2 < deg) pfn = teP[eb + idx + 2];
      float d0 = nh.x * P0.x + nh.y * P0.y + nh.z * P0.z + nh.w * P0.w;
      float d1 = nh.x * P1.x + nh.y * P1.y + nh.z * P1.z + nh.w * P1.w;
      float d2 = nh.x * P2.x + nh.y * P2.y + nh.z * P2.z + nh.w * P2.w;
      float d3 = nh.x * P3.x + nh.y * P3.y + nh.z * P3.z + nh.w * P3.w;
      // packed 4-value butterfly: lane ends with full sum of d_{l32&3}
      float x01 = (l32 & 1) ? d1 : d0;
      float y01 = (l32 & 1) ? d0 : d1;
      x01 += __shfl_xor(y01, 1);
      float x23 = (l32 & 1) ? d3 : d2;
      float y23 = (l32 & 1) ? d2 : d3;
      x23 += __shfl_xor(y23, 1);
      float xa = (l32 & 2) ? x23 : x01;
      float xb = (l32 & 2) ? x01 : x23;
      xa += __shfl_xor(xb, 2);
      xa += __shfl_xor(xa, 4);
      xa += __shfl_xor(xa, 8);
      xa += __shfl_xor(xa, 16);
      const float eL = __expf(fminf(fmaxf(xa, -10.f), 10.f));
      const float e0 = eL;                 // head lp
      const float e1 = __shfl_xor(eL, 1);  // head lp^1
      const float e2 = __shfl_xor(eL, 2);  // head lp^2
      const float e3 = __shfl_xor(eL, 3);  // head lp^3
      b0.x = fmaf(e0, nh.x, b0.x); b0.y = fmaf(e0, nh.y, b0.y);
      b0.z = fmaf(e0, nh.z, b0.z); b0.w = fmaf(e0, nh.w, b0.w);
      b1.x = fmaf(e1, nh.x, b1.x); b1.y = fmaf(e1, nh.y, b1.y);
      b1.z = fmaf(e1, nh.z, b1.z); b1.w = fmaf(e1, nh.w, b1.w);
      b2.x = fmaf(e2, nh.x, b2.x); b2.y = fmaf(e2, nh.y, b2.y);
      b2.z = fmaf(e2, nh.z, b2.z); b2.w = fmaf(e2, nh.w, b2.w);
      b3.x = fmaf(e3, nh.x, b3.x); b3.y = fmaf(e3, nh.y, b3.y);
      b3.z = fmaf(e3, nh.z, b3.z); b3.w = fmaf(e3, nh.w, b3.w);
      s0 += e0; s1 += e1; s2 += e2; s3 += e3;
    }
    const float i0 = 1.f / (s0 + 1e-8f);
    const float i1 = 1.f / (s1 + 1e-8f);
    const float i2 = 1.f / (s2 + 1e-8f);
    const float i3 = 1.f / (s3 + 1e-8f);
    float4 o0 = {b0.x * i0, b0.y * i0, b0.z * i0, b0.w * i0};
    float4 o1 = {b1.x * i1, b1.y * i1, b1.z * i1, b1.w * i1};
    float4 o2 = {b2.x * i2, b2.y * i2, b2.z * i2, b2.w * i2};
    float4 o3 = {b3.x * i3, b3.y * i3, b3.z * i3, b3.w * i3};
    const int sb = kk * 512 + l32 * 4;
    *(float4*)&sPA[sb + ((lp ^ 0) << 7)] = o0;
    *(float4*)&sPA[sb + ((lp ^ 1) << 7)] = o1;
    *(float4*)&sPA[sb + ((lp ^ 2) << 7)] = o2;
    *(float4*)&sPA[sb + ((lp ^ 3) << 7)] = o3;
  }
  __syncthreads();

  // P3: kg[n,c] = sum_d agg[n,h(c),d]*vT[d,c] (regs); kg^2 -> sQ (Q dead).
  {
    const int c = t & 127;
    const int g4 = (t >> 7) * 4;
    const int h = c >> 5;
    float acc0 = 0.f, acc1 = 0.f, acc2 = 0.f, acc3 = 0.f;
    const float* agg0 = &sPA[(g4 + 0) * 512 + h * 128];
    const float* agg1 = &sPA[(g4 + 1) * 512 + h * 128];
    const float* agg2 = &sPA[(g4 + 2) * 512 + h * 128];
    const float* agg3 = &sPA[(g4 + 3) * 512 + h * 128];
#pragma unroll 4
    for (int d4 = 0; d4 < 32; ++d4) {
      const float4 a0 = *(const float4*)&agg0[d4 * 4];
      const float4 a1 = *(const float4*)&agg1[d4 * 4];
      const float4 a2 = *(const float4*)&agg2[d4 * 4];
      const float4 a3 = *(const float4*)&agg3[d4 * 4];
      const float v0 = vT[(d4 * 4 + 0) * 128 + c];
      const float v1 = vT[(d4 * 4 + 1) * 128 + c];
      const float v2 = vT[(d4 * 4 + 2) * 128 + c];
      const float v3 = vT[(d4 * 4 + 3) * 128 + c];
      acc0 = fmaf(a0.x, v0, acc0); acc0 = fmaf(a0.y, v1, acc0);
      acc0 = fmaf(a0.z, v2, acc0); acc0 = fmaf(a0.w, v3, acc0);
      acc1 = fmaf(a1.x, v0, acc1); acc1 = fmaf(a1.y, v1, acc1);
      acc1 = fmaf(a1.z, v2, acc1); acc1 = fmaf(a1.w, v3, acc1);
      acc2 = fmaf(a2.x, v0, acc2); acc2 = fmaf(a2.y, v1, acc2);
      acc2 = fmaf(a2.z, v2, acc2); acc2 = fmaf(a2.w, v3, acc2);
      acc3 = fmaf(a3.x, v0, acc3); acc3 = fmaf(a3.y, v1, acc3);
      acc3 = fmaf(a3.z, v2, acc3); acc3 = fmaf(a3.w, v3, acc3);
    }
    sQ[(g4 + 0) * 128 + c] = acc0 * acc0;
    sQ[(g4 + 1) * 128 + c] = acc1 * acc1;
    sQ[(g4 + 2) * 128 + c] = acc2 * acc2;
    sQ[(g4 + 3) * 128 + c] = acc3 * acc3;
  }
  __syncthreads();

  // P4: S[n,r] = sum_c kg2[n,c] * wrel2[r,c]; coalesced store.
  {
    const int nn = t >> 5;  // 0..7
    const int r = t & 31;
    const float* kg2 = &sQ[nn * 128];
    const float* w2 = &wrel2[r * 128];
    float acc = 0.f;
#pragma unroll 4
    for (int c4 = 0; c4 < 32; ++c4) {
      const float4 a = *(const float4*)&kg2[c4 * 4];
      const float4 b = *(const float4*)&w2[c4 * 4];
      acc = fmaf(a.x, b.x, acc); acc = fmaf(a.y, b.y, acc);
      acc = fmaf(a.z, b.z, acc); acc = fmaf(a.w, b.w, acc);
    }
    S[(size_t)(base + nn) * 32 + r] = acc;
  }
}

// ---------------------------------------------------------------------------
// K4: per-node softmax over w(e)=S[n,ty]*S[tail,ty] + weighted gather.
// S[n] row in one lane register (per-edge S[n][ty] = __shfl, no gather);
// aggregation with 4 independent row loads in flight.
// Half-wave per node (2 nodes/wave), float4 dims, chunk=32.
// ---------------------------------------------------------------------------
__global__ __launch_bounds__(256) void k_out2(
    const float* __restrict__ ent, const float* __restrict__ S,
    const int* __restrict__ off, const int2* __restrict__ teP,
    float* __restrict__ out) {
  const int t = threadIdx.x;
  const int wid = t >> 6;
  const int half = (t >> 5) & 1;
  const int l32 = t & 31;
  const int kk = wid * 2 + half;
  const int n = blockIdx.x * 8 + kk;
  if (n >= N_ENT) return;
  const int eb = off[n];
  const int deg = off[n + 1] - eb;
  const float sn = S[(size_t)n * 32 + l32];  // lane l holds S[n][l]
  float4 acc = {0, 0, 0, 0};
  float m = 0.f, ssum = 0.f;
  for (int b = 0; b < deg; b += 32) {
    const int idx = b + l32;
    const bool val = idx < deg;
    const int e = eb + (val ? idx : 0);
    const int2 tp = teP[e];
    const int tl = tp.x;
    const int ty = tp.y;
    const float snv = __shfl(sn, ty, 32);
    float w = val ? snv * S[(size_t)tl * 32 + ty] : -1.f;
    float cm = w;
#pragma unroll
    for (int k = 1; k < 32; k <<= 1) cm = fmaxf(cm, __shfl_xor(cm, k));
    const float mnew = fmaxf(m, cm);
    const float scale = __expf(m - mnew);
    const float el = val ? __expf(w - mnew) : 0.f;
    float cs = el;
#pragma unroll
    for (int k = 1; k < 32; k <<= 1) cs += __shfl_xor(cs, k);
    ssum = ssum * scale + cs;
    acc.x *= scale; acc.y *= scale; acc.z *= scale; acc.w *= scale;
    const int cnt = (deg - b < 32) ? deg - b : 32;
    for (int j0 = 0; j0 < cnt; j0 += 4) {
      const int rem = cnt - j0;
      const int t0 = __shfl(tl, j0 + 0, 32);
      float4 r0 = *(const float4*)&ent[(size_t)t0 * D + l32 * 4];
      float4 r1, r2, r3;
      if (rem > 1) {
        const int t1 = __shfl(tl, j0 + 1, 32);
        r1 = *(const float4*)&ent[(size_t)t1 * D + l32 * 4];
      }
      if (rem > 2) {
        const int t2 = __shfl(tl, j0 + 2, 32);
        r2 = *(const float4*)&ent[(size_t)t2 * D + l32 * 4];
      }
      if (rem > 3) {
        const int t3 = __shfl(tl, j0 + 3, 32);
        r3 = *(const float4*)&ent[(size_t)t3 * D + l32 * 4];
      }
      const float w0 = __shfl(el, j0 + 0, 32);
      acc.x = fmaf(w0, r0.x, acc.x); acc.y = fmaf(w0, r0.y, acc.y);
      acc.z = fmaf(w0, r0.z, acc.z); acc.w = fmaf(w0, r0.w, acc.w);
      if (rem > 1) {
        const float w1 = __shfl(el, j0 + 1, 32);
        acc.x = fmaf(w1, r1.x, acc.x); acc.y = fmaf(w1, r1.y, acc.y);
        acc.z = fmaf(w1, r1.z, acc.z); acc.w = fmaf(w1, r1.w, acc.w);
      }
      if (rem > 2) {
        const float w2 = __shfl(el, j0 + 2, 32);
        acc.x = fmaf(w2, r2.x, acc.x); acc.y = fmaf(w2, r2.y, acc.y);
        acc.z = fmaf(w2, r2.z, acc.z); acc.w = fmaf(w2, r2.w, acc.w);
      }
      if (rem > 3) {
        const float w3 = __shfl(el, j0 + 3, 32);
        acc.x = fmaf(w3, r3.x, acc.x); acc.y = fmaf(w3, r3.y, acc.y);
        acc.z = fmaf(w3, r3.z, acc.z); acc.w = fmaf(w3, r3.w, acc.w);
      }
    }
    m = mnew;
  }
  const float inv = (deg > 0) ? 1.f / ssum : 0.f;
  float4 o = {acc.x * inv, acc.y * inv, acc.z * inv, acc.w * inv};
  *(float4*)&out[(size_t)n * D + l32 * 4] = o;
}

// ---------------------------------------------------------------------------
// Workspace (byte-identical footprint to the proven round-2 layout):
//   S [N*32] fp32; off[N+2], cur[N], deg[N], bsum/bbase[SCAN_NB] int;
//   teP [E] int2; kTt [128*128] fp32. wrel2 ALIASES cur (dead after scatter).
// d_out timeline: Q (k_qproj) -> consumed by k_fused -> output (k_out2).
// ---------------------------------------------------------------------------
extern "C" void kernel_launch(void* const* d_in, const int* in_sizes, int n_in,
                              void* d_out, int out_size, void* d_ws,
                              size_t ws_size, hipStream_t stream) {
  const float* ent = (const float*)d_in[0];
  const float* wrel = (const float*)d_in[3];
  const float* qT = (const float*)d_in[4];
  const float* kT = (const float*)d_in[5];
  const float* vT = (const float*)d_in[6];
  const int* eidx = (const int*)d_in[7];
  const int* etype = (const int*)d_in[8];
  const int* head = eidx;
  const int* tail = eidx + N_EDGE;

  float* S = (float*)d_ws;
  int* off = (int*)(S + (size_t)N_ENT * 32);
  int* cur = off + (N_ENT + 2);  // +2 keeps teP 8-byte aligned
  int* deg = cur + N_ENT;
  int* bsum = deg + N_ENT;
  int* bbase = bsum + SCAN_NB;
  int2* teP = (int2*)(bbase + SCAN_NB);
  float* kTt = (float*)(teP + N_EDGE);
  float* wrel2 = (float*)cur;  // 16 KB of the 400 KB dead cursor array
  float* qkg = (float*)d_out;

  hipMemsetAsync(deg, 0, N_ENT * sizeof(int), stream);
  k_hist<<<(N_EDGE + 255) / 256, 256, 0, stream>>>(head, deg);
  k_scan1<<<SCAN_NB, 256, 0, stream>>>(deg, bsum);
  k_scan2<<<1, 256, 0, stream>>>(bsum, bbase, off);
  k_scan3<<<SCAN_NB, 256, 0, stream>>>(deg, bbase, off, cur);
  k_scatter<<<(N_EDGE + 255) / 256, 256, 0, stream>>>(head, tail, etype, cur,
                                                      teP);
  k_prep<<<17, 256, 0, stream>>>(kT, kTt, wrel, wrel2);
  k_qproj<<<(N_ENT + 127) / 128, 512, 0, stream>>>(ent, qT, qkg);
  k_fused<<<N_ENT / 8, 256, 0, stream>>>(ent, wrel, kTt, vT, wrel2, qkg, S,
                                         off, teP);
  k_out2<<<(N_ENT + 7) / 8, 256, 0, stream>>>(ent, S, off, teP, qkg);
}

// Round 10
// 501.612 us; speedup vs baseline: 1.2720x; 1.1048x over previous
//
#include <hip/hip_runtime.h>
#include <cstdint>

#define D 128
#define H 4
#define N_ENT 100000
#define N_EDGE 400000
#define R 32

#define SCAN_NB ((N_ENT + 511) / 512)  // 196 blocks of 512 elements

// ---------------------------------------------------------------------------
// CSR build: histogram -> hierarchical scan -> scatter (permuted packed
// (tail,etype) int2).
// ---------------------------------------------------------------------------
__global__ void k_hist(const int* __restrict__ head, int* __restrict__ deg) {
  const int e = blockIdx.x * 256 + threadIdx.x;
  if (e < N_EDGE) atomicAdd(&deg[head[e]], 1);
}

__global__ __launch_bounds__(256) void k_scan1(const int* __restrict__ deg,
                                               int* __restrict__ bsum) {
  const int t = threadIdx.x;
  const int i = blockIdx.x * 512 + t * 2;
  int v0 = (i < N_ENT) ? deg[i] : 0;
  int v1 = (i + 1 < N_ENT) ? deg[i + 1] : 0;
  int s = v0 + v1;
#pragma unroll
  for (int k = 1; k < 64; k <<= 1) s += __shfl_xor(s, k);
  __shared__ int ws[4];
  if ((t & 63) == 0) ws[t >> 6] = s;
  __syncthreads();
  if (t == 0) bsum[blockIdx.x] = ws[0] + ws[1] + ws[2] + ws[3];
}

__global__ __launch_bounds__(256) void k_scan2(const int* __restrict__ bsum,
                                               int* __restrict__ bbase,
                                               int* __restrict__ off) {
  __shared__ int sh[256];
  const int t = threadIdx.x;
  const int v = (t < SCAN_NB) ? bsum[t] : 0;
  sh[t] = v;
  __syncthreads();
  for (int d = 1; d < 256; d <<= 1) {
    const int u = (t >= d) ? sh[t - d] : 0;
    __syncthreads();
    sh[t] += u;
    __syncthreads();
  }
  if (t < SCAN_NB) bbase[t] = sh[t] - v;
  if (t == SCAN_NB - 1) off[N_ENT] = sh[t];
}

__global__ __launch_bounds__(256) void k_scan3(const int* __restrict__ deg,
                                               const int* __restrict__ bbase,
                                               int* __restrict__ off,
                                               int* __restrict__ cur) {
  __shared__ int sh[256];
  const int t = threadIdx.x;
  const int i = blockIdx.x * 512 + t * 2;
  const int v0 = (i < N_ENT) ? deg[i] : 0;
  const int v1 = (i + 1 < N_ENT) ? deg[i + 1] : 0;
  const int s = v0 + v1;
  sh[t] = s;
  __syncthreads();
  for (int d = 1; d < 256; d <<= 1) {
    const int u = (t >= d) ? sh[t - d] : 0;
    __syncthreads();
    sh[t] += u;
    __syncthreads();
  }
  const int ex = sh[t] - s + bbase[blockIdx.x];
  if (i < N_ENT) {
    off[i] = ex;
    cur[i] = ex;
  }
  if (i + 1 < N_ENT) {
    off[i + 1] = ex + v0;
    cur[i + 1] = ex + v0;
  }
}

__global__ void k_scatter(const int* __restrict__ head,
                          const int* __restrict__ tail,
                          const int* __restrict__ etype, int* __restrict__ cur,
                          int2* __restrict__ teP) {
  const int e = blockIdx.x * 256 + threadIdx.x;
  if (e >= N_EDGE) return;
  const int hd = head[e];
  const int pos = atomicAdd(&cur[hd], 1);
  teP[pos] = make_int2(tail[e], etype[e] - 1);
}

// ---------------------------------------------------------------------------
// kTt[j*128+i] = kT[i*128+j]
// ---------------------------------------------------------------------------
__global__ __launch_bounds__(256) void k_tr(const float* __restrict__ in,
                                            float* __restrict__ out) {
  __shared__ float tile[32][33];
  const int bx = blockIdx.x & 3, by = blockIdx.x >> 2;
  const int c = threadIdx.x & 31;
  const int r0 = (threadIdx.x >> 5) * 4;
#pragma unroll
  for (int i = 0; i < 4; ++i)
    tile[r0 + i][c] = in[(by * 32 + r0 + i) * 128 + bx * 32 + c];
  __syncthreads();
#pragma unroll
  for (int i = 0; i < 4; ++i)
    out[(bx * 32 + r0 + i) * 128 + by * 32 + c] = tile[c][r0 + i];
}

// ---------------------------------------------------------------------------
// K1: Q = entity_emb @ qTrans   (Q in d_out; consumed & overwritten by k_fused)
// ---------------------------------------------------------------------------
__global__ __launch_bounds__(512) void k_qproj(const float* __restrict__ ent,
                                               const float* __restrict__ qT,
                                               float* __restrict__ Q) {
  __shared__ float sT[D * D];
  __shared__ float rows[D * 128];
  const int t = threadIdx.x;
  const int n0 = blockIdx.x * 128;
#pragma unroll
  for (int s = 0; s < 8; ++s) {
    const int idx = (s * 512 + t) * 4;
    *(float4*)&sT[idx] = *(const float4*)&qT[idx];
  }
  {
    const int g = t & 3;
    const int n = t >> 2;
    const int node = n0 + n;
    if (node < N_ENT) {
      const float* src = ent + (size_t)node * D;
#pragma unroll
      for (int s = 0; s < 8; ++s) {
        const int i = s * 16 + g * 4;
        float4 v = *(const float4*)&src[i];
        rows[(i + 0) * 128 + n] = v.x;
        rows[(i + 1) * 128 + n] = v.y;
        rows[(i + 2) * 128 + n] = v.z;
        rows[(i + 3) * 128 + n] = v.w;
      }
    } else {
#pragma unroll
      for (int s = 0; s < 8; ++s) {
        const int i = s * 16 + g * 4;
        rows[(i + 0) * 128 + n] = 0.f;
        rows[(i + 1) * 128 + n] = 0.f;
        rows[(i + 2) * 128 + n] = 0.f;
        rows[(i + 3) * 128 + n] = 0.f;
      }
    }
  }
  __syncthreads();
  const int jj = t & 15;
  const int ee = t >> 4;
  float acc[4][8];
#pragma unroll
  for (int a = 0; a < 4; ++a)
#pragma unroll
    for (int b = 0; b < 8; ++b) acc[a][b] = 0.f;
#pragma unroll 4
  for (int i = 0; i < D; ++i) {
    float4 b0 = *(float4*)&sT[i * D + jj * 8];
    float4 b1 = *(float4*)&sT[i * D + jj * 8 + 4];
    float4 a0 = *(float4*)&rows[i * 128 + ee * 4];
    float bv[8] = {b0.x, b0.y, b0.z, b0.w, b1.x, b1.y, b1.z, b1.w};
    float av[4] = {a0.x, a0.y, a0.z, a0.w};
#pragma unroll
    for (int a = 0; a < 4; ++a)
#pragma unroll
      for (int b = 0; b < 8; ++b) acc[a][b] = fmaf(av[a], bv[b], acc[a][b]);
  }
#pragma unroll
  for (int a = 0; a < 4; ++a) {
    const int node = n0 + ee * 4 + a;
    if (node < N_ENT) {
      float4 o0 = {acc[a][0], acc[a][1], acc[a][2], acc[a][3]};
      float4 o1 = {acc[a][4], acc[a][5], acc[a][6], acc[a][7]};
      *(float4*)&Q[(size_t)node * D + jj * 8] = o0;
      *(float4*)&Q[(size_t)node * D + jj * 8 + 4] = o1;
    }
  }
}

// ---------------------------------------------------------------------------
// K2: fused all-heads attention — BYTE-EXACT revert to the Round-2-bench
// version (measured 234 us twice). (256,8) clamp-32 with its ~186 MB spill
// traffic is ACCEPTED: R8/R9 "clean" alternatives measured 355/342 us.
// 8 nodes/block (one per 32-lane half-wave), 20 KB LDS (sP/sAgg aliased).
// ---------------------------------------------------------------------------
__global__ __launch_bounds__(256, 8) void k_fused(
    const float* __restrict__ ent, const float* __restrict__ wrel,
    const float* __restrict__ kTt, const float* __restrict__ vT, float* qkg,
    const int* __restrict__ off, const int2* __restrict__ teP) {
  __shared__ float sQ[8 * 128];    //  4 KB
  __shared__ float sPA[8 * 512];   // 16 KB, P then Agg (aliased)
  const int t = threadIdx.x;
  const int base = blockIdx.x * 8;

  const int wid = t >> 6;
  const int half = (t >> 5) & 1;
  const int l32 = t & 31;
  const int kk = wid * 2 + half;
  const int n = base + kk;

  // P0: stage Q rows
  {
    const int k = t >> 5;
    const int c4 = (t & 31) * 4;
    *(float4*)&sQ[k * 128 + c4] =
        *(const float4*)&qkg[(size_t)(base + k) * D + c4];
  }

  // hoisted: CSR range + first edge gather (latency overlaps P1)
  const int eb = off[n];
  const int deg = off[n + 1] - eb;
  float4 xv = {0, 0, 0, 0}, rv = {0, 0, 0, 0};
  if (deg > 0) {
    const int2 pf = teP[eb];
    xv = *(const float4*)&ent[(size_t)pf.x * D + l32 * 4];
    rv = *(const float4*)&wrel[(size_t)pf.y * D + l32 * 4];
  }
  __syncthreads();

  // P1: cooperative P-compute. thread t: i = t&127, sub = t>>7 (heads 2sub..)
  {
    const int i = t & 127;
    const int sub = t >> 7;
    float pp[2][8];
#pragma unroll
    for (int hh = 0; hh < 2; ++hh)
#pragma unroll
      for (int k = 0; k < 8; ++k) pp[hh][k] = 0.f;
#pragma unroll
    for (int hh = 0; hh < 2; ++hh) {
      const int h = sub * 2 + hh;
#pragma unroll 2
      for (int c4 = 0; c4 < 8; ++c4) {
        const float kv0 = kTt[(h * 32 + c4 * 4 + 0) * 128 + i];
        const float kv1 = kTt[(h * 32 + c4 * 4 + 1) * 128 + i];
        const float kv2 = kTt[(h * 32 + c4 * 4 + 2) * 128 + i];
        const float kv3 = kTt[(h * 32 + c4 * 4 + 3) * 128 + i];
#pragma unroll
        for (int k = 0; k < 8; ++k) {
          const float4 q = *(const float4*)&sQ[k * 128 + h * 32 + c4 * 4];
          pp[hh][k] = fmaf(kv0, q.x, pp[hh][k]);
          pp[hh][k] = fmaf(kv1, q.y, pp[hh][k]);
          pp[hh][k] = fmaf(kv2, q.z, pp[hh][k]);
          pp[hh][k] = fmaf(kv3, q.w, pp[hh][k]);
        }
      }
    }
#pragma unroll
    for (int hh = 0; hh < 2; ++hh)
#pragma unroll
      for (int k = 0; k < 8; ++k)
        sPA[k * 512 + (sub * 2 + hh) * 128 + i] = pp[hh][k];
  }
  __syncthreads();

  // P2: edge loop. half-wave owns one node. lane lp = l32&3 carries head
  // (lp^m) in accumulator b_m; store offset un-permutes.
  {
    const int lp = l32 & 3;
    const float4 P0 = *(const float4*)&sPA[kk * 512 + 0 * 128 + l32 * 4];
    const float4 P1 = *(const float4*)&sPA[kk * 512 + 1 * 128 + l32 * 4];
    const float4 P2 = *(const float4*)&sPA[kk * 512 + 2 * 128 + l32 * 4];
    const float4 P3 = *(const float4*)&sPA[kk * 512 + 3 * 128 + l32 * 4];
    float4 b0 = {0, 0, 0, 0}, b1 = {0, 0, 0, 0};
    float4 b2 = {0, 0, 0, 0}, b3 = {0, 0, 0, 0};
    float s0 = 0.f, s1 = 0.f, s2 = 0.f, s3 = 0.f;
    for (int idx = 0; idx < deg; ++idx) {
      const float4 cx = xv, cr = rv;
      if (idx + 1 < deg) {
        const int2 pf = teP[eb + idx + 1];
        xv = *(const float4*)&ent[(size_t)pf.x * D + l32 * 4];
        rv = *(const float4*)&wrel[(size_t)pf.y * D + l32 * 4];
      }
      const float4 nh = {cx.x * cr.x, cx.y * cr.y, cx.z * cr.z, cx.w * cr.w};
      float d0 = nh.x * P0.x + nh.y * P0.y + nh.z * P0.z + nh.w * P0.w;
      float d1 = nh.x * P1.x + nh.y * P1.y + nh.z * P1.z + nh.w * P1.w;
      float d2 = nh.x * P2.x + nh.y * P2.y + nh.z * P2.z + nh.w * P2.w;
      float d3 = nh.x * P3.x + nh.y * P3.y + nh.z * P3.z + nh.w * P3.w;
      // packed 4-value butterfly: lane ends with full sum of d_{l32&3}
      float x01 = (l32 & 1) ? d1 : d0;
      float y01 = (l32 & 1) ? d0 : d1;
      x01 += __shfl_xor(y01, 1);
      float x23 = (l32 & 1) ? d3 : d2;
      float y23 = (l32 & 1) ? d2 : d3;
      x23 += __shfl_xor(y23, 1);
      float xa = (l32 & 2) ? x23 : x01;
      float xb = (l32 & 2) ? x01 : x23;
      xa += __shfl_xor(xb, 2);
      xa += __shfl_xor(xa, 4);
      xa += __shfl_xor(xa, 8);
      xa += __shfl_xor(xa, 16);
      const float eL = __expf(fminf(fmaxf(xa, -10.f), 10.f));
      const float e0 = eL;                 // head lp
      const float e1 = __shfl_xor(eL, 1);  // head lp^1
      const float e2 = __shfl_xor(eL, 2);  // head lp^2
      const float e3 = __shfl_xor(eL, 3);  // head lp^3
      b0.x = fmaf(e0, nh.x, b0.x); b0.y = fmaf(e0, nh.y, b0.y);
      b0.z = fmaf(e0, nh.z, b0.z); b0.w = fmaf(e0, nh.w, b0.w);
      b1.x = fmaf(e1, nh.x, b1.x); b1.y = fmaf(e1, nh.y, b1.y);
      b1.z = fmaf(e1, nh.z, b1.z); b1.w = fmaf(e1, nh.w, b1.w);
      b2.x = fmaf(e2, nh.x, b2.x); b2.y = fmaf(e2, nh.y, b2.y);
      b2.z = fmaf(e2, nh.z, b2.z); b2.w = fmaf(e2, nh.w, b2.w);
      b3.x = fmaf(e3, nh.x, b3.x); b3.y = fmaf(e3, nh.y, b3.y);
      b3.z = fmaf(e3, nh.z, b3.z); b3.w = fmaf(e3, nh.w, b3.w);
      s0 += e0; s1 += e1; s2 += e2; s3 += e3;
    }
    // b_m/s_m belong to head (lp^m): divide and store at head offset lp^m.
    const float i0 = 1.f / (s0 + 1e-8f);
    const float i1 = 1.f / (s1 + 1e-8f);
    const float i2 = 1.f / (s2 + 1e-8f);
    const float i3 = 1.f / (s3 + 1e-8f);
    float4 o0 = {b0.x * i0, b0.y * i0, b0.z * i0, b0.w * i0};
    float4 o1 = {b1.x * i1, b1.y * i1, b1.z * i1, b1.w * i1};
    float4 o2 = {b2.x * i2, b2.y * i2, b2.z * i2, b2.w * i2};
    float4 o3 = {b3.x * i3, b3.y * i3, b3.z * i3, b3.w * i3};
    const int sb = kk * 512 + l32 * 4;
    *(float4*)&sPA[sb + ((lp ^ 0) << 7)] = o0;
    *(float4*)&sPA[sb + ((lp ^ 1) << 7)] = o1;
    *(float4*)&sPA[sb + ((lp ^ 2) << 7)] = o2;
    *(float4*)&sPA[sb + ((lp ^ 3) << 7)] = o3;
  }
  __syncthreads();

  // P3: cooperative vT projection. thread t: col c, 4 nodes per group.
  {
    const int c = t & 127;
    const int g4 = (t >> 7) * 4;
    const int h = c >> 5;
    float acc0 = 0.f, acc1 = 0.f, acc2 = 0.f, acc3 = 0.f;
    const float* agg0 = &sPA[(g4 + 0) * 512 + h * 128];
    const float* agg1 = &sPA[(g4 + 1) * 512 + h * 128];
    const float* agg2 = &sPA[(g4 + 2) * 512 + h * 128];
    const float* agg3 = &sPA[(g4 + 3) * 512 + h * 128];
#pragma unroll 4
    for (int d4 = 0; d4 < 32; ++d4) {
      const float4 a0 = *(const float4*)&agg0[d4 * 4];
      const float4 a1 = *(const float4*)&agg1[d4 * 4];
      const float4 a2 = *(const float4*)&agg2[d4 * 4];
      const float4 a3 = *(const float4*)&agg3[d4 * 4];
      const float v0 = vT[(d4 * 4 + 0) * 128 + c];
      const float v1 = vT[(d4 * 4 + 1) * 128 + c];
      const float v2 = vT[(d4 * 4 + 2) * 128 + c];
      const float v3 = vT[(d4 * 4 + 3) * 128 + c];
      acc0 = fmaf(a0.x, v0, acc0); acc0 = fmaf(a0.y, v1, acc0);
      acc0 = fmaf(a0.z, v2, acc0); acc0 = fmaf(a0.w, v3, acc0);
      acc1 = fmaf(a1.x, v0, acc1); acc1 = fmaf(a1.y, v1, acc1);
      acc1 = fmaf(a1.z, v2, acc1); acc1 = fmaf(a1.w, v3, acc1);
      acc2 = fmaf(a2.x, v0, acc2); acc2 = fmaf(a2.y, v1, acc2);
      acc2 = fmaf(a2.z, v2, acc2); acc2 = fmaf(a2.w, v3, acc2);
      acc3 = fmaf(a3.x, v0, acc3); acc3 = fmaf(a3.y, v1, acc3);
      acc3 = fmaf(a3.z, v2, acc3); acc3 = fmaf(a3.w, v3, acc3);
    }
    qkg[(size_t)(base + g4 + 0) * D + c] = acc0;
    qkg[(size_t)(base + g4 + 1) * D + c] = acc1;
    qkg[(size_t)(base + g4 + 2) * D + c] = acc2;
    qkg[(size_t)(base + g4 + 3) * D + c] = acc3;
  }
}

// ---------------------------------------------------------------------------
// K3: S[n,r] = sum_d kg[n,d]^2 * wrel[r,d]^2  (Round-2-bench version)
// ---------------------------------------------------------------------------
__global__ __launch_bounds__(256) void k_S(const float* __restrict__ kg,
                                           const float* __restrict__ wrel,
                                           float* __restrict__ S) {
  __shared__ float sB[D * 32];
  __shared__ float sA[D * 64];
  const int t = threadIdx.x;
  const int n0 = blockIdx.x * 64;
  {
    const int r = t & 31;
    const int qg = t >> 5;
#pragma unroll
    for (int s = 0; s < 4; ++s) {
      const int d = qg * 16 + s * 4;
      float4 b = *(const float4*)&wrel[(size_t)r * D + d];
      sB[(d + 0) * 32 + r] = b.x * b.x;
      sB[(d + 1) * 32 + r] = b.y * b.y;
      sB[(d + 2) * 32 + r] = b.z * b.z;
      sB[(d + 3) * 32 + r] = b.w * b.w;
    }
  }
  {
    const int nn = t & 63;
    const int dg = t >> 6;
    const int node = n0 + nn;
#pragma unroll
    for (int s = 0; s < 8; ++s) {
      const int d = dg * 32 + s * 4;
      float4 a = {0, 0, 0, 0};
      if (node < N_ENT) a = *(const float4*)&kg[(size_t)node * D + d];
      sA[(d + 0) * 64 + nn] = a.x * a.x;
      sA[(d + 1) * 64 + nn] = a.y * a.y;
      sA[(d + 2) * 64 + nn] = a.z * a.z;
      sA[(d + 3) * 64 + nn] = a.w * a.w;
    }
  }
  __syncthreads();
  const int nn2 = t >> 2;
  const int rg = t & 3;
  float acc[8];
#pragma unroll
  for (int c = 0; c < 8; ++c) acc[c] = 0.f;
#pragma unroll 4
  for (int d = 0; d < D; ++d) {
    const float a = sA[d * 64 + nn2];
    float4 b0 = *(float4*)&sB[d * 32 + rg * 8];
    float4 b1 = *(float4*)&sB[d * 32 + rg * 8 + 4];
    acc[0] = fmaf(a, b0.x, acc[0]);
    acc[1] = fmaf(a, b0.y, acc[1]);
    acc[2] = fmaf(a, b0.z, acc[2]);
    acc[3] = fmaf(a, b0.w, acc[3]);
    acc[4] = fmaf(a, b1.x, acc[4]);
    acc[5] = fmaf(a, b1.y, acc[5]);
    acc[6] = fmaf(a, b1.z, acc[6]);
    acc[7] = fmaf(a, b1.w, acc[7]);
  }
  const int node = n0 + nn2;
  if (node < N_ENT) {
    float4 o0 = {acc[0], acc[1], acc[2], acc[3]};
    float4 o1 = {acc[4], acc[5], acc[6], acc[7]};
    *(float4*)&S[(size_t)node * 32 + rg * 8] = o0;
    *(float4*)&S[(size_t)node * 32 + rg * 8 + 4] = o1;
  }
}

// ---------------------------------------------------------------------------
// K4: per-node softmax over w(e)=S[n,ty]*S[tail,ty] + weighted gather.
// R9-proven version: half-wave per node, S[n] row in one lane register
// (per-edge S[n][ty] = __shfl), 4 independent row loads in flight.
// ---------------------------------------------------------------------------
__global__ __launch_bounds__(256) void k_out2(
    const float* __restrict__ ent, const float* __restrict__ S,
    const int* __restrict__ off, const int2* __restrict__ teP,
    float* __restrict__ out) {
  const int t = threadIdx.x;
  const int wid = t >> 6;
  const int half = (t >> 5) & 1;
  const int l32 = t & 31;
  const int kk = wid * 2 + half;
  const int n = blockIdx.x * 8 + kk;
  if (n >= N_ENT) return;
  const int eb = off[n];
  const int deg = off[n + 1] - eb;
  const float sn = S[(size_t)n * 32 + l32];  // lane l holds S[n][l]
  float4 acc = {0, 0, 0, 0};
  float m = 0.f, ssum = 0.f;
  for (int b = 0; b < deg; b += 32) {
    const int idx = b + l32;
    const bool val = idx < deg;
    const int e = eb + (val ? idx : 0);
    const int2 tp = teP[e];
    const int tl = tp.x;
    const int ty = tp.y;
    const float snv = __shfl(sn, ty, 32);
    float w = val ? snv * S[(size_t)tl * 32 + ty] : -1.f;
    float cm = w;
#pragma unroll
    for (int k = 1; k < 32; k <<= 1) cm = fmaxf(cm, __shfl_xor(cm, k));
    const float mnew = fmaxf(m, cm);
    const float scale = __expf(m - mnew);
    const float el = val ? __expf(w - mnew) : 0.f;
    float cs = el;
#pragma unroll
    for (int k = 1; k < 32; k <<= 1) cs += __shfl_xor(cs, k);
    ssum = ssum * scale + cs;
    acc.x *= scale; acc.y *= scale; acc.z *= scale; acc.w *= scale;
    const int cnt = (deg - b < 32) ? deg - b : 32;
    for (int j0 = 0; j0 < cnt; j0 += 4) {
      const int rem = cnt - j0;
      const int t0 = __shfl(tl, j0 + 0, 32);
      float4 r0 = *(const float4*)&ent[(size_t)t0 * D + l32 * 4];
      float4 r1, r2, r3;
      if (rem > 1) {
        const int t1 = __shfl(tl, j0 + 1, 32);
        r1 = *(const float4*)&ent[(size_t)t1 * D + l32 * 4];
      }
      if (rem > 2) {
        const int t2 = __shfl(tl, j0 + 2, 32);
        r2 = *(const float4*)&ent[(size_t)t2 * D + l32 * 4];
      }
      if (rem > 3) {
        const int t3 = __shfl(tl, j0 + 3, 32);
        r3 = *(const float4*)&ent[(size_t)t3 * D + l32 * 4];
      }
      const float w0 = __shfl(el, j0 + 0, 32);
      acc.x = fmaf(w0, r0.x, acc.x); acc.y = fmaf(w0, r0.y, acc.y);
      acc.z = fmaf(w0, r0.z, acc.z); acc.w = fmaf(w0, r0.w, acc.w);
      if (rem > 1) {
        const float w1 = __shfl(el, j0 + 1, 32);
        acc.x = fmaf(w1, r1.x, acc.x); acc.y = fmaf(w1, r1.y, acc.y);
        acc.z = fmaf(w1, r1.z, acc.z); acc.w = fmaf(w1, r1.w, acc.w);
      }
      if (rem > 2) {
        const float w2 = __shfl(el, j0 + 2, 32);
        acc.x = fmaf(w2, r2.x, acc.x); acc.y = fmaf(w2, r2.y, acc.y);
        acc.z = fmaf(w2, r2.z, acc.z); acc.w = fmaf(w2, r2.w, acc.w);
      }
      if (rem > 3) {
        const float w3 = __shfl(el, j0 + 3, 32);
        acc.x = fmaf(w3, r3.x, acc.x); acc.y = fmaf(w3, r3.y, acc.y);
        acc.z = fmaf(w3, r3.z, acc.z); acc.w = fmaf(w3, r3.w, acc.w);
      }
    }
    m = mnew;
  }
  const float inv = (deg > 0) ? 1.f / ssum : 0.f;
  float4 o = {acc.x * inv, acc.y * inv, acc.z * inv, acc.w * inv};
  *(float4*)&out[(size_t)n * D + l32 * 4] = o;
}

// ---------------------------------------------------------------------------
// Workspace (round-2 layout):
//   S [N*32] fp32; off[N+2], cur[N], deg[N], bsum/bbase[SCAN_NB] int;
//   teP [E] int2; kTt [128*128] fp32.
// d_out timeline: Q (k_qproj) -> kg (k_fused, in place) -> output (k_out2).
// ---------------------------------------------------------------------------
extern "C" void kernel_launch(void* const* d_in, const int* in_sizes, int n_in,
                              void* d_out, int out_size, void* d_ws,
                              size_t ws_size, hipStream_t stream) {
  const float* ent = (const float*)d_in[0];
  const float* wrel = (const float*)d_in[3];
  const float* qT = (const float*)d_in[4];
  const float* kT = (const float*)d_in[5];
  const float* vT = (const float*)d_in[6];
  const int* eidx = (const int*)d_in[7];
  const int* etype = (const int*)d_in[8];
  const int* head = eidx;
  const int* tail = eidx + N_EDGE;

  float* S = (float*)d_ws;
  int* off = (int*)(S + (size_t)N_ENT * 32);
  int* cur = off + (N_ENT + 2);  // +2 keeps teP 8-byte aligned
  int* deg = cur + N_ENT;
  int* bsum = deg + N_ENT;
  int* bbase = bsum + SCAN_NB;
  int2* teP = (int2*)(bbase + SCAN_NB);
  float* kTt = (float*)(teP + N_EDGE);
  float* qkg = (float*)d_out;

  hipMemsetAsync(deg, 0, N_ENT * sizeof(int), stream);
  k_hist<<<(N_EDGE + 255) / 256, 256, 0, stream>>>(head, deg);
  k_scan1<<<SCAN_NB, 256, 0, stream>>>(deg, bsum);
  k_scan2<<<1, 256, 0, stream>>>(bsum, bbase, off);
  k_scan3<<<SCAN_NB, 256, 0, stream>>>(deg, bbase, off, cur);
  k_scatter<<<(N_EDGE + 255) / 256, 256, 0, stream>>>(head, tail, etype, cur,
                                                      teP);
  k_tr<<<16, 256, 0, stream>>>(kT, kTt);
  k_qproj<<<(N_ENT + 127) / 128, 512, 0, stream>>>(ent, qT, qkg);
  k_fused<<<N_ENT / 8, 256, 0, stream>>>(ent, wrel, kTt, vT, qkg, off, teP);
  k_S<<<(N_ENT + 63) / 64, 256, 0, stream>>>(qkg, wrel, S);
  k_out2<<<(N_ENT + 7) / 8, 256, 0, stream>>>(ent, S, off, teP, qkg);
}